// Round 4
// baseline (903.778 us; speedup 1.0000x reference)
//
#include <hip/hip_runtime.h>

// ---------- types & helpers ----------
using f32x4     = __attribute__((ext_vector_type(4))) float;
using bf16x8    = __attribute__((ext_vector_type(8))) short;
using ushort4_t = __attribute__((ext_vector_type(4))) unsigned short;
using ushort8_t = __attribute__((ext_vector_type(8))) unsigned short;
using uint4_t   = __attribute__((ext_vector_type(4))) unsigned int;

__device__ __forceinline__ unsigned short f2bf(float f) {
    unsigned u = __builtin_bit_cast(unsigned, f);
    u += 0x7fffu + ((u >> 16) & 1u);   // RNE
    return (unsigned short)(u >> 16);
}
__device__ __forceinline__ float bf2f(unsigned short h) {
    return __builtin_bit_cast(float, (unsigned)h << 16);
}

__device__ __forceinline__ float wave_sum(float v) {
#pragma unroll
    for (int off = 32; off > 0; off >>= 1) v += __shfl_xor(v, off, 64);
    return v;
}
__device__ __forceinline__ float wave_max(float v) {
#pragma unroll
    for (int off = 32; off > 0; off >>= 1) v = fmaxf(v, __shfl_xor(v, off, 64));
    return v;
}

#define GLP(p)  ((const __attribute__((address_space(1))) void*)(p))
#define LDSP(p) ((__attribute__((address_space(3))) void*)(p))

// ---------- f32 -> bf16 bulk convert ----------
__global__ __launch_bounds__(256) void cvt_bf16(const float* __restrict__ in,
                                                unsigned short* __restrict__ out, long n8) {
    long i = (long)blockIdx.x * 256 + threadIdx.x;
    long stride = (long)gridDim.x * 256;
    for (; i < n8; i += stride) {
        const float4* p = (const float4*)(in + i * 8);
        float4 a = p[0], b = p[1];
        ushort8_t v;
        v[0] = f2bf(a.x); v[1] = f2bf(a.y); v[2] = f2bf(a.z); v[3] = f2bf(a.w);
        v[4] = f2bf(b.x); v[5] = f2bf(b.y); v[6] = f2bf(b.z); v[7] = f2bf(b.w);
        *(ushort8_t*)(out + i * 8) = v;
    }
}

// ---------- weight pack (transpose -> bf16, [N][K] row-major) ----------
__global__ void pack_w(const float* __restrict__ Wc, const float* __restrict__ Wi,
                       unsigned short* __restrict__ Wp) {
    int n = blockIdx.x, k = blockIdx.y * 256 + threadIdx.x;
    float v = (n < 768) ? Wc[(size_t)k * 768 + n] : Wi[(size_t)k * 768 + (n - 768)];
    Wp[(size_t)n * 2048 + k] = f2bf(v);
}

__global__ void pack_wq(const float* __restrict__ Wq, unsigned short* __restrict__ Wqt) {
    int n = blockIdx.x, k = blockIdx.y * 256 + threadIdx.x;
    Wqt[(size_t)n * 768 + k] = f2bf(Wq[(size_t)k * 768 + n]);
}

// ---------- 256x256 bf16 GEMM, BK=64, 2-deep pipeline, progressive lgkm ----------
// C[M][N] = A[M][K] @ Bt[N][K]^T + bias.  8 waves (2Mx4N), per-wave 128x64.
// LDS: 2 bufs x (256 rows x 64 bf16) per operand = 128 KiB total.
// T2 perm: 16B chunk (row r, slot s=k/8) -> phys chunk r*8 + ((s+r)&7).
//   Fragment k-step ks flips slot by +4 -> phys elem offset ^32.
// Per tile: bar; STAGE(T+1) 8x gload_lds; vmcnt(8); bar; 4x{ds_reads | lgkm(N) | 16 MFMA}.
__global__ __launch_bounds__(512, 1) void gemm8(
    const unsigned short* __restrict__ A, const unsigned short* __restrict__ Bt,
    const float* __restrict__ bias0, const float* __restrict__ bias1, int nsplit,
    float* __restrict__ C, int N, int K, int NTN)
{
    __shared__ unsigned short LA[2][16384];
    __shared__ unsigned short LB[2][16384];
    const int tid = threadIdx.x, lane = tid & 63, wid = tid >> 6;

    int nwg = (int)gridDim.x, bid = (int)blockIdx.x;
    if ((nwg & 7) == 0) { int cpx = nwg >> 3; bid = (bid & 7) * cpx + (bid >> 3); }  // T1
    const int tn = bid % NTN, tm = bid / NTN;
    const size_t m0 = (size_t)tm * 256, n0 = (size_t)tn * 256;
    const int NT = K >> 6;

    const int wr = wid >> 2, wc = wid & 3;
    const int wm = wr * 128, wn = wc * 64;
    const int fr = lane & 15, fs = lane >> 4;

    // staging: 2048 chunks/tile/operand; thread covers c = tid + 512*i
    const unsigned short *gA0p, *gA1p, *gA2p, *gA3p, *gB0p, *gB1p, *gB2p, *gB3p;
    int o0, o1, o2, o3;
    {
        int c, r, s;
        c = tid;        r = c >> 3; s = ((c & 7) - r) & 7; gA0p = A + (m0 + r) * K + s * 8; gB0p = Bt + (n0 + r) * K + s * 8; o0 = c * 8;
        c = tid + 512;  r = c >> 3; s = ((c & 7) - r) & 7; gA1p = A + (m0 + r) * K + s * 8; gB1p = Bt + (n0 + r) * K + s * 8; o1 = c * 8;
        c = tid + 1024; r = c >> 3; s = ((c & 7) - r) & 7; gA2p = A + (m0 + r) * K + s * 8; gB2p = Bt + (n0 + r) * K + s * 8; o2 = c * 8;
        c = tid + 1536; r = c >> 3; s = ((c & 7) - r) & 7; gA3p = A + (m0 + r) * K + s * 8; gB3p = Bt + (n0 + r) * K + s * 8; o3 = c * 8;
    }

#define STAGE8(koff, b) do { \
    __builtin_amdgcn_global_load_lds(GLP(gA0p + (koff)), LDSP(&LA[b][o0]), 16, 0, 0); \
    __builtin_amdgcn_global_load_lds(GLP(gA1p + (koff)), LDSP(&LA[b][o1]), 16, 0, 0); \
    __builtin_amdgcn_global_load_lds(GLP(gA2p + (koff)), LDSP(&LA[b][o2]), 16, 0, 0); \
    __builtin_amdgcn_global_load_lds(GLP(gA3p + (koff)), LDSP(&LA[b][o3]), 16, 0, 0); \
    __builtin_amdgcn_global_load_lds(GLP(gB0p + (koff)), LDSP(&LB[b][o0]), 16, 0, 0); \
    __builtin_amdgcn_global_load_lds(GLP(gB1p + (koff)), LDSP(&LB[b][o1]), 16, 0, 0); \
    __builtin_amdgcn_global_load_lds(GLP(gB2p + (koff)), LDSP(&LB[b][o2]), 16, 0, 0); \
    __builtin_amdgcn_global_load_lds(GLP(gB3p + (koff)), LDSP(&LB[b][o3]), 16, 0, 0); \
} while (0)

    // fragment LDS offsets (ks=0); ks=1 -> ^32
    int offA[8], offB[4];
#pragma unroll
    for (int mf = 0; mf < 8; ++mf) {
        int r = wm + mf * 16 + fr;
        offA[mf] = (r * 8 + ((fs + r) & 7)) * 8;
    }
#pragma unroll
    for (int nf = 0; nf < 4; ++nf) {
        int r = wn + nf * 16 + fr;
        offB[nf] = (r * 8 + ((fs + r) & 7)) * 8;
    }

    f32x4 acc[8][4];
#pragma unroll
    for (int i = 0; i < 8; ++i)
#pragma unroll
        for (int j = 0; j < 4; ++j) acc[i][j] = (f32x4){0.f, 0.f, 0.f, 0.f};

    STAGE8(0, 0);   // prologue: tile 0 -> buf 0

    for (int T = 0; T < NT; ++T) {
        const int buf = T & 1;
        __builtin_amdgcn_s_barrier();            // all waves done reading buf^1
        if (T + 1 < NT) {
            STAGE8((size_t)(T + 1) * 64, buf ^ 1);
            asm volatile("s_waitcnt vmcnt(8)" ::: "memory");   // tile T landed (own)
        } else {
            asm volatile("s_waitcnt vmcnt(0)" ::: "memory");
        }
        __builtin_amdgcn_s_barrier();            // tile T landed (all waves)
        __builtin_amdgcn_sched_barrier(0);

        bf16x8 a0[4], a1[4], a2[4], a3[4], bv0[4], bv1[4];
        // group 1: a0 (Mh0,k0), bv0 (k0), a1 (Mh1,k0) -- 12 reads
#pragma unroll
        for (int mf = 0; mf < 4; ++mf) a0[mf] = *(const bf16x8*)&LA[buf][offA[mf]];
#pragma unroll
        for (int nf = 0; nf < 4; ++nf) bv0[nf] = *(const bf16x8*)&LB[buf][offB[nf]];
#pragma unroll
        for (int mf = 0; mf < 4; ++mf) a1[mf] = *(const bf16x8*)&LA[buf][offA[4 + mf]];
        __builtin_amdgcn_sched_barrier(0);
        asm volatile("s_waitcnt lgkmcnt(4)" ::: "memory");     // a0,bv0 done; a1 may fly
        __builtin_amdgcn_sched_barrier(0);
        __builtin_amdgcn_s_setprio(1);
#pragma unroll
        for (int mf = 0; mf < 4; ++mf)
#pragma unroll
            for (int nf = 0; nf < 4; ++nf)
                acc[mf][nf] = __builtin_amdgcn_mfma_f32_16x16x32_bf16(a0[mf], bv0[nf], acc[mf][nf], 0, 0, 0);
        __builtin_amdgcn_s_setprio(0);

        // group 2: bv1 (k1), a2 (Mh0,k1)
#pragma unroll
        for (int nf = 0; nf < 4; ++nf) bv1[nf] = *(const bf16x8*)&LB[buf][offB[nf] ^ 32];
#pragma unroll
        for (int mf = 0; mf < 4; ++mf) a2[mf] = *(const bf16x8*)&LA[buf][offA[mf] ^ 32];
        __builtin_amdgcn_sched_barrier(0);
        asm volatile("s_waitcnt lgkmcnt(8)" ::: "memory");     // a1 done; bv1,a2 may fly
        __builtin_amdgcn_sched_barrier(0);
        __builtin_amdgcn_s_setprio(1);
#pragma unroll
        for (int mf = 0; mf < 4; ++mf)
#pragma unroll
            for (int nf = 0; nf < 4; ++nf)
                acc[4 + mf][nf] = __builtin_amdgcn_mfma_f32_16x16x32_bf16(a1[mf], bv0[nf], acc[4 + mf][nf], 0, 0, 0);
        __builtin_amdgcn_s_setprio(0);

        // group 3: a3 (Mh1,k1)
#pragma unroll
        for (int mf = 0; mf < 4; ++mf) a3[mf] = *(const bf16x8*)&LA[buf][offA[4 + mf] ^ 32];
        __builtin_amdgcn_sched_barrier(0);
        asm volatile("s_waitcnt lgkmcnt(4)" ::: "memory");     // bv1,a2 done; a3 may fly
        __builtin_amdgcn_sched_barrier(0);
        __builtin_amdgcn_s_setprio(1);
#pragma unroll
        for (int mf = 0; mf < 4; ++mf)
#pragma unroll
            for (int nf = 0; nf < 4; ++nf)
                acc[mf][nf] = __builtin_amdgcn_mfma_f32_16x16x32_bf16(a2[mf], bv1[nf], acc[mf][nf], 0, 0, 0);
        __builtin_amdgcn_s_setprio(0);

        asm volatile("s_waitcnt lgkmcnt(0)" ::: "memory");     // a3 done
        __builtin_amdgcn_sched_barrier(0);
        __builtin_amdgcn_s_setprio(1);
#pragma unroll
        for (int mf = 0; mf < 4; ++mf)
#pragma unroll
            for (int nf = 0; nf < 4; ++nf)
                acc[4 + mf][nf] = __builtin_amdgcn_mfma_f32_16x16x32_bf16(a3[mf], bv1[nf], acc[4 + mf][nf], 0, 0, 0);
        __builtin_amdgcn_s_setprio(0);
    }
#undef STAGE8

    // epilogue  (C/D layout: col = lane&15, row = (lane>>4)*4 + r)
#pragma unroll
    for (int nf = 0; nf < 4; ++nf) {
        int col = (int)n0 + wn + nf * 16 + fr;
        float bs = (col < nsplit) ? bias0[col] : bias1[col - nsplit];
#pragma unroll
        for (int mf = 0; mf < 8; ++mf) {
            size_t rowb = m0 + wm + mf * 16 + fs * 4;
#pragma unroll
            for (int r = 0; r < 4; ++r)
                C[(rowb + r) * N + col] = acc[mf][nf][r] + bs;
        }
    }
}

// ---------- fallback GEMM (f32 A with inline cvt, small-ws path) ----------
__global__ __launch_bounds__(256) void gemm_fb(
    const float* __restrict__ A, const unsigned short* __restrict__ Bt,
    const float* __restrict__ bias0, const float* __restrict__ bias1, int nsplit,
    float* __restrict__ C, int M, int N, int K)
{
    const int tid = threadIdx.x, lane = tid & 63, wid = tid >> 6;
    const int m0 = blockIdx.x * 128, n0 = blockIdx.y * 128;
    __shared__ unsigned short Al[128 * 40];
    __shared__ unsigned short Bl[128 * 40];

    f32x4 acc[4][4];
#pragma unroll
    for (int i = 0; i < 4; ++i)
#pragma unroll
        for (int j = 0; j < 4; ++j) acc[i][j] = (f32x4){0.f, 0.f, 0.f, 0.f};

    const int wm_ = (wid >> 1) * 64, wn_ = (wid & 1) * 64;
    const int fr = lane & 15, fk = (lane >> 4) * 8;

    for (int k0 = 0; k0 < K; k0 += 32) {
        __syncthreads();
#pragma unroll
        for (int it = 0; it < 4; ++it) {
            int idx = tid + it * 256;
            int row = idx >> 3, c4 = idx & 7;
            float4 v = *(const float4*)(A + (size_t)(m0 + row) * K + k0 + c4 * 4);
            ushort4_t h;
            h.x = f2bf(v.x); h.y = f2bf(v.y); h.z = f2bf(v.z); h.w = f2bf(v.w);
            *(ushort4_t*)&Al[row * 40 + c4 * 4] = h;
        }
#pragma unroll
        for (int it = 0; it < 2; ++it) {
            int idx = tid + it * 256;
            int row = idx >> 2, c4 = idx & 3;
            uint4_t v = *(const uint4_t*)(Bt + (size_t)(n0 + row) * K + k0 + c4 * 8);
            *(uint4_t*)&Bl[row * 40 + c4 * 8] = v;
        }
        __syncthreads();

        bf16x8 af[4], bfr[4];
#pragma unroll
        for (int i = 0; i < 4; ++i) af[i]  = *(const bf16x8*)&Al[(wm_ + i * 16 + fr) * 40 + fk];
#pragma unroll
        for (int j = 0; j < 4; ++j) bfr[j] = *(const bf16x8*)&Bl[(wn_ + j * 16 + fr) * 40 + fk];
#pragma unroll
        for (int i = 0; i < 4; ++i)
#pragma unroll
            for (int j = 0; j < 4; ++j)
                acc[i][j] = __builtin_amdgcn_mfma_f32_16x16x32_bf16(af[i], bfr[j], acc[i][j], 0, 0, 0);
    }

#pragma unroll
    for (int j = 0; j < 4; ++j) {
        int col = n0 + wn_ + j * 16 + (lane & 15);
        float bs = (col < nsplit) ? bias0[col] : bias1[col - nsplit];
#pragma unroll
        for (int i = 0; i < 4; ++i) {
            int rowb = m0 + wm_ + i * 16 + (lane >> 4) * 4;
#pragma unroll
            for (int r = 0; r < 4; ++r)
                C[(size_t)(rowb + r) * N + col] = acc[i][j][r] + bs;
        }
    }
}

// ---------- wm kernel ----------
__global__ __launch_bounds__(256) void wm_kernel(
    const float* __restrict__ qf_g, const float* __restrict__ imgCE,
    const float* __restrict__ g1, const float* __restrict__ b1,
    float* __restrict__ wm_g)
{
    const int b = blockIdx.x, tid = threadIdx.x, lane = tid & 63, wid = tid >> 6;
    __shared__ float qf[14 * 768];
    __shared__ float wmr[14][100];

    const float4* src = (const float4*)(qf_g + (size_t)b * 14 * 768);
    for (int i = tid; i < 14 * 768 / 4; i += 256) ((float4*)qf)[i] = src[i];
    __syncthreads();

    for (int n = wid; n < 100; n += 4) {
        const float* row = imgCE + ((size_t)b * 100 + n) * 1536;
        float r[12];
#pragma unroll
        for (int j = 0; j < 12; ++j) r[j] = row[lane + 64 * j];
        for (int t = 0; t < 14; ++t) {
            const float* q = qf + t * 768;
            float s = 0.f;
#pragma unroll
            for (int j = 0; j < 12; ++j) s = fmaf(r[j], q[lane + 64 * j], s);
            s = wave_sum(s);
            if (lane == 0) wmr[t][n] = s;
        }
    }
    __syncthreads();

    for (int t = wid; t < 14; t += 4) {
        float x0 = wmr[t][lane];
        float x1 = (lane + 64 < 100) ? wmr[t][lane + 64] : 0.f;
        float s = wave_sum(x0 + x1);
        float q = wave_sum(x0 * x0 + x1 * x1);
        float mu = s * (1.f / 100.f);
        float var = q * (1.f / 100.f) - mu * mu;
        float rs = rsqrtf(var + 1e-3f);
        float* dst = wm_g + ((size_t)b * 14 + t) * 100;
        {
            float v = (x0 - mu) * rs * g1[lane] + b1[lane];
            dst[lane] = v > 0.f ? v : 0.f;
        }
        if (lane + 64 < 100) {
            float v = (x1 - mu) * rs * g1[lane + 64] + b1[lane + 64];
            dst[lane + 64] = v > 0.f ? v : 0.f;
        }
    }
}

// ---------- ques path ----------
__global__ __launch_bounds__(256) void ques_kernel(
    const float* __restrict__ qf_g, const float* __restrict__ qe_g,
    const float* __restrict__ imgCE, const float* __restrict__ wm_g,
    const float* __restrict__ g2, const float* __restrict__ b2,
    const float* __restrict__ g3, const float* __restrict__ b3,
    const float* __restrict__ wqa, const float* __restrict__ bqa,
    float* __restrict__ out_q)
{
    const int b = blockIdx.x, tid = threadIdx.x, lane = tid & 63, wid = tid >> 6;
    __shared__ float qe[14 * 768];
    __shared__ float wm[14 * 100];
    __shared__ float red[4][28];
    __shared__ float mu_s[14], rs_s[14], qa_s[14], qw_s[14];

    {
        const float4* src = (const float4*)(qe_g + (size_t)b * 14 * 768);
        for (int i = tid; i < 14 * 768 / 4; i += 256) ((float4*)qe)[i] = src[i];
        const float* ws = wm_g + (size_t)b * 1400;
        for (int i = tid; i < 1400; i += 256) wm[i] = ws[i];
    }
    __syncthreads();

    float a0[14], a1[14], a2[14];
#pragma unroll
    for (int t = 0; t < 14; ++t) { a0[t] = 0.f; a1[t] = 0.f; a2[t] = 0.f; }

    const float* ie_base = imgCE + (size_t)b * 100 * 1536 + 768;
    for (int n = 0; n < 100; ++n) {
        const float* ie = ie_base + (size_t)n * 1536;
        float e0 = ie[tid], e1 = ie[tid + 256], e2 = ie[tid + 512];
#pragma unroll
        for (int t = 0; t < 14; ++t) {
            float w = wm[t * 100 + n];
            a0[t] = fmaf(w, e0, a0[t]); a1[t] = fmaf(w, e1, a1[t]); a2[t] = fmaf(w, e2, a2[t]);
        }
    }
#pragma unroll
    for (int t = 0; t < 14; ++t) {
        a0[t] += qe[t * 768 + tid];
        a1[t] += qe[t * 768 + tid + 256];
        a2[t] += qe[t * 768 + tid + 512];
    }
#pragma unroll
    for (int t = 0; t < 14; ++t) {
        float s = wave_sum(a0[t] + a1[t] + a2[t]);
        float q = wave_sum(a0[t] * a0[t] + a1[t] * a1[t] + a2[t] * a2[t]);
        if (lane == 0) { red[wid][t] = s; red[wid][14 + t] = q; }
    }
    __syncthreads();
    if (tid < 14) {
        float s = red[0][tid] + red[1][tid] + red[2][tid] + red[3][tid];
        float q = red[0][14 + tid] + red[1][14 + tid] + red[2][14 + tid] + red[3][14 + tid];
        float mu = s * (1.f / 768.f);
        float var = q * (1.f / 768.f) - mu * mu;
        mu_s[tid] = mu; rs_s[tid] = rsqrtf(var + 1e-3f);
    }
    __syncthreads();

    float ga = g2[tid], ba = b2[tid], gb = g2[tid + 256], bb = b2[tid + 256],
          gc = g2[tid + 512], bc_ = b2[tid + 512];
    float w0 = wqa[tid], w1 = wqa[tid + 256], w2 = wqa[tid + 512];
#pragma unroll
    for (int t = 0; t < 14; ++t) {
        float mu = mu_s[t], rs = rs_s[t];
        float v0 = fmaxf((a0[t] - mu) * rs * ga + ba, 0.f);
        float v1 = fmaxf((a1[t] - mu) * rs * gb + bb, 0.f);
        float v2 = fmaxf((a2[t] - mu) * rs * gc + bc_, 0.f);
        float p = wave_sum(v0 * w0 + v1 * w1 + v2 * w2);
        if (lane == 0) red[wid][t] = p;
    }
    __syncthreads();
    if (tid < 14) qa_s[tid] = red[0][tid] + red[1][tid] + red[2][tid] + red[3][tid] + bqa[0];
    __syncthreads();
    if (tid == 0) {
        float s = 0.f;
        for (int t = 0; t < 14; ++t) s += qa_s[t];
        float mu = s * (1.f / 14.f);
        float q = 0.f;
        for (int t = 0; t < 14; ++t) { float d = qa_s[t] - mu; q += d * d; }
        float rs = rsqrtf(q * (1.f / 14.f) + 1e-3f);
        float e[14], mx = -1e30f;
        for (int t = 0; t < 14; ++t) { e[t] = (qa_s[t] - mu) * rs * g3[t] + b3[t]; mx = fmaxf(mx, e[t]); }
        float se = 0.f;
        for (int t = 0; t < 14; ++t) { e[t] = expf(e[t] - mx); se += e[t]; }
        float inv = 1.f / se;
        for (int t = 0; t < 14; ++t) qw_s[t] = e[t] * inv;
    }
    __syncthreads();

    const float* qf = qf_g + (size_t)b * 14 * 768;
#pragma unroll
    for (int c = 0; c < 3; ++c) {
        int h = tid + c * 256;
        float o = 0.f;
#pragma unroll
        for (int t = 0; t < 14; ++t) o = fmaf(qw_s[t], qf[t * 768 + h], o);
        out_q[(size_t)b * 768 + h] = o;
    }
}

// ---------- img path ----------
__global__ __launch_bounds__(256) void img_kernel(
    const float* __restrict__ img_feat, const unsigned short* __restrict__ imf_bf, int use_bf,
    const float* __restrict__ qe_g,
    const float* __restrict__ imgCE, const float* __restrict__ wm_g,
    const float* __restrict__ g4, const float* __restrict__ b4,
    const float* __restrict__ g5, const float* __restrict__ b5,
    const float* __restrict__ wia, const float* __restrict__ bia,
    float* __restrict__ out_i)
{
    const int b = blockIdx.x, tid = threadIdx.x, lane = tid & 63, wid = tid >> 6;
    __shared__ float qe[14 * 768];
    __shared__ float wm[14 * 100];
    __shared__ float red[4][20];
    __shared__ float mu_s[10], rs_s[10];
    __shared__ float ia_s[100], iw_s[100];

    {
        const float4* src = (const float4*)(qe_g + (size_t)b * 14 * 768);
        for (int i = tid; i < 14 * 768 / 4; i += 256) ((float4*)qe)[i] = src[i];
        const float* ws = wm_g + (size_t)b * 1400;
        for (int i = tid; i < 1400; i += 256) wm[i] = ws[i];
    }
    __syncthreads();

    float g4a = g4[tid], b4a = b4[tid], g4b = g4[tid + 256], b4b = b4[tid + 256],
          g4c = g4[tid + 512], b4c = b4[tid + 512];
    float wa = wia[tid], wb = wia[tid + 256], wc_ = wia[tid + 512];

    for (int g = 0; g < 10; ++g) {
        float t0[10], t1[10], t2[10];
#pragma unroll
        for (int i = 0; i < 10; ++i) { t0[i] = 0.f; t1[i] = 0.f; t2[i] = 0.f; }
#pragma unroll
        for (int t = 0; t < 14; ++t) {
            float q0 = qe[t * 768 + tid], q1 = qe[t * 768 + tid + 256], q2 = qe[t * 768 + tid + 512];
#pragma unroll
            for (int i = 0; i < 10; ++i) {
                float w = wm[t * 100 + g * 10 + i];
                t0[i] = fmaf(w, q0, t0[i]); t1[i] = fmaf(w, q1, t1[i]); t2[i] = fmaf(w, q2, t2[i]);
            }
        }
#pragma unroll
        for (int i = 0; i < 10; ++i) {
            const float* ie = imgCE + ((size_t)b * 100 + g * 10 + i) * 1536 + 768;
            t0[i] += ie[tid]; t1[i] += ie[tid + 256]; t2[i] += ie[tid + 512];
            float s = wave_sum(t0[i] + t1[i] + t2[i]);
            float q = wave_sum(t0[i] * t0[i] + t1[i] * t1[i] + t2[i] * t2[i]);
            if (lane == 0) { red[wid][i] = s; red[wid][10 + i] = q; }
        }
        __syncthreads();
        if (tid < 10) {
            float s = red[0][tid] + red[1][tid] + red[2][tid] + red[3][tid];
            float q = red[0][10 + tid] + red[1][10 + tid] + red[2][10 + tid] + red[3][10 + tid];
            float mu = s * (1.f / 768.f);
            float var = q * (1.f / 768.f) - mu * mu;
            mu_s[tid] = mu; rs_s[tid] = rsqrtf(var + 1e-3f);
        }
        __syncthreads();
#pragma unroll
        for (int i = 0; i < 10; ++i) {
            float mu = mu_s[i], rs = rs_s[i];
            float v0 = fmaxf((t0[i] - mu) * rs * g4a + b4a, 0.f);
            float v1 = fmaxf((t1[i] - mu) * rs * g4b + b4b, 0.f);
            float v2 = fmaxf((t2[i] - mu) * rs * g4c + b4c, 0.f);
            float p = wave_sum(v0 * wa + v1 * wb + v2 * wc_);
            if (lane == 0) red[wid][i] = p;
        }
        __syncthreads();
        if (tid < 10) ia_s[g * 10 + tid] = red[0][tid] + red[1][tid] + red[2][tid] + red[3][tid] + bia[0];
        __syncthreads();
    }

    if (wid == 0) {
        float x0 = ia_s[lane];
        float x1 = (lane + 64 < 100) ? ia_s[lane + 64] : 0.f;
        float s = wave_sum(x0 + x1);
        float q = wave_sum(x0 * x0 + x1 * x1);
        float mu = s * 0.01f;
        float var = q * 0.01f - mu * mu;
        float rs = rsqrtf(var + 1e-3f);
        float v0 = (x0 - mu) * rs * g5[lane] + b5[lane];
        float v1 = (lane + 64 < 100) ? (x1 - mu) * rs * g5[lane + 64] + b5[lane + 64] : -1e30f;
        float mx = wave_max(fmaxf(v0, v1));
        float e0 = expf(v0 - mx);
        float e1 = (lane + 64 < 100) ? expf(v1 - mx) : 0.f;
        float se = wave_sum(e0 + e1);
        float inv = 1.f / se;
        iw_s[lane] = e0 * inv;
        if (lane + 64 < 100) iw_s[lane + 64] = e1 * inv;
    }
    __syncthreads();

    // img_atten_feat = sum_n iw[n] * img_feat[b,n,:]
    if (use_bf) {
        const unsigned short* imf = imf_bf + (size_t)b * 100 * 2048;
        float acc8[8];
#pragma unroll
        for (int j = 0; j < 8; ++j) acc8[j] = 0.f;
        for (int n = 0; n < 100; ++n) {
            ushort8_t v = *(const ushort8_t*)(imf + (size_t)n * 2048 + tid * 8);
            float w = iw_s[n];
#pragma unroll
            for (int j = 0; j < 8; ++j) acc8[j] = fmaf(w, bf2f(v[j]), acc8[j]);
        }
        float4* dst = (float4*)(out_i + (size_t)b * 2048);
        float4 oA = {acc8[0], acc8[1], acc8[2], acc8[3]};
        float4 oB = {acc8[4], acc8[5], acc8[6], acc8[7]};
        dst[tid * 2] = oA; dst[tid * 2 + 1] = oB;
    } else {
        const float* imf = img_feat + (size_t)b * 100 * 2048;
#pragma unroll
        for (int c = 0; c < 2; ++c) {
            int col = tid + c * 256;
            float4 acc = {0.f, 0.f, 0.f, 0.f};
            for (int n = 0; n < 100; ++n) {
                float4 v = ((const float4*)(imf + (size_t)n * 2048))[col];
                float w = iw_s[n];
                acc.x = fmaf(w, v.x, acc.x); acc.y = fmaf(w, v.y, acc.y);
                acc.z = fmaf(w, v.z, acc.z); acc.w = fmaf(w, v.w, acc.w);
            }
            ((float4*)(out_i + (size_t)b * 2048))[col] = acc;
        }
    }
}

// ---------- launch ----------
extern "C" void kernel_launch(void* const* d_in, const int* in_sizes, int n_in,
                              void* d_out, int out_size, void* d_ws, size_t ws_size,
                              hipStream_t stream)
{
    const float* img_feat = (const float*)d_in[0];
    const float* ques_feat = (const float*)d_in[1];
    const float* Wc = (const float*)d_in[2];
    const float* bc = (const float*)d_in[3];
    const float* Wq = (const float*)d_in[4];
    const float* bq = (const float*)d_in[5];
    const float* Wi = (const float*)d_in[6];
    const float* bi = (const float*)d_in[7];
    const float* wqa = (const float*)d_in[8];
    const float* bqa = (const float*)d_in[9];
    const float* wia = (const float*)d_in[10];
    const float* bia = (const float*)d_in[11];
    const float* g1 = (const float*)d_in[12]; const float* b1 = (const float*)d_in[13];
    const float* g2 = (const float*)d_in[14]; const float* b2 = (const float*)d_in[15];
    const float* g3 = (const float*)d_in[16]; const float* b3 = (const float*)d_in[17];
    const float* g4 = (const float*)d_in[18]; const float* b4 = (const float*)d_in[19];
    const float* g5 = (const float*)d_in[20]; const float* b5 = (const float*)d_in[21];

    // workspace layout (bytes)
    const size_t SZ_WP   = 1536u * 2048u * 2u;
    const size_t SZ_WQT  = 768u * 768u * 2u;
    const size_t SZ_IMG  = 51200ull * 1536u * 4u;
    const size_t SZ_QE   = 7168u * 768u * 4u;
    const size_t SZ_WM   = 512u * 1400u * 4u;
    const size_t SZ_ABF  = 51200ull * 2048u * 2u;
    const size_t SZ_QBF  = 7168u * 768u * 2u;

    const size_t OFF_WP  = 0;
    const size_t OFF_WQT = OFF_WP + SZ_WP;
    const size_t OFF_IMG = OFF_WQT + SZ_WQT;
    const size_t OFF_QE  = OFF_IMG + SZ_IMG;
    const size_t OFF_WM  = OFF_QE + SZ_QE;
    const size_t OFF_ABF = OFF_WM + SZ_WM;
    const size_t OFF_QBF = OFF_ABF + SZ_ABF;
    const size_t NEED_FB  = OFF_ABF;
    const size_t NEED_NEW = OFF_QBF + SZ_QBF;

    if (ws_size < NEED_FB) return;

    char* ws = (char*)d_ws;
    unsigned short* Wp  = (unsigned short*)(ws + OFF_WP);
    unsigned short* Wqt = (unsigned short*)(ws + OFF_WQT);
    float* imgCE = (float*)(ws + OFF_IMG);
    float* qe    = (float*)(ws + OFF_QE);
    float* wm    = (float*)(ws + OFF_WM);

    float* out_img = (float*)d_out;                   // [512][2048]
    float* out_q   = (float*)d_out + 512 * 2048;      // [512][768]

    hipLaunchKernelGGL(pack_w,  dim3(1536, 8), dim3(256), 0, stream, Wc, Wi, Wp);
    hipLaunchKernelGGL(pack_wq, dim3(768, 3),  dim3(256), 0, stream, Wq, Wqt);

    if (ws_size >= NEED_NEW) {
        unsigned short* Abf = (unsigned short*)(ws + OFF_ABF);
        unsigned short* Qbf = (unsigned short*)(ws + OFF_QBF);
        hipLaunchKernelGGL(cvt_bf16, dim3(2048), dim3(256), 0, stream,
                           img_feat, Abf, (long)(51200ull * 2048u / 8u));
        hipLaunchKernelGGL(cvt_bf16, dim3(1024), dim3(256), 0, stream,
                           ques_feat, Qbf, (long)(7168u * 768u / 8u));
        // imgCE = img_feat @ [Wc|Wi] + [bc|bi]   (M=51200, N=1536, K=2048)
        hipLaunchKernelGGL(gemm8, dim3(1200), dim3(512), 0, stream,
                           Abf, Wp, bc, bi, 768, imgCE, 1536, 2048, 6);
        // qe = ques_feat @ Wq + bq               (M=7168, N=768, K=768)
        hipLaunchKernelGGL(gemm8, dim3(84), dim3(512), 0, stream,
                           Qbf, Wqt, bq, bq, 768, qe, 768, 768, 3);

        hipLaunchKernelGGL(wm_kernel, dim3(512), dim3(256), 0, stream,
                           ques_feat, imgCE, g1, b1, wm);
        hipLaunchKernelGGL(ques_kernel, dim3(512), dim3(256), 0, stream,
                           ques_feat, qe, imgCE, wm, g2, b2, g3, b3, wqa, bqa, out_q);
        hipLaunchKernelGGL(img_kernel, dim3(512), dim3(256), 0, stream,
                           img_feat, Abf, 1, qe, imgCE, wm, g4, b4, g5, b5, wia, bia, out_img);
    } else {
        hipLaunchKernelGGL(gemm_fb, dim3(400, 12), dim3(256), 0, stream,
                           img_feat, Wp, bc, bi, 768, imgCE, 51200, 1536, 2048);
        hipLaunchKernelGGL(gemm_fb, dim3(56, 6), dim3(256), 0, stream,
                           ques_feat, Wqt, bq, bq, 768, qe, 7168, 768, 768);

        hipLaunchKernelGGL(wm_kernel, dim3(512), dim3(256), 0, stream,
                           ques_feat, imgCE, g1, b1, wm);
        hipLaunchKernelGGL(ques_kernel, dim3(512), dim3(256), 0, stream,
                           ques_feat, qe, imgCE, wm, g2, b2, g3, b3, wqa, bqa, out_q);
        hipLaunchKernelGGL(img_kernel, dim3(512), dim3(256), 0, stream,
                           img_feat, (const unsigned short*)nullptr, 0, qe, imgCE, wm,
                           g4, b4, g5, b5, wia, bia, out_img);
    }
}

// Round 5
// 810.018 us; speedup vs baseline: 1.1157x; 1.1157x over previous
//
#include <hip/hip_runtime.h>

// ---------- types & helpers ----------
using f32x4     = __attribute__((ext_vector_type(4))) float;
using bf16x8    = __attribute__((ext_vector_type(8))) short;
using ushort4_t = __attribute__((ext_vector_type(4))) unsigned short;
using ushort8_t = __attribute__((ext_vector_type(8))) unsigned short;
using uint4_t   = __attribute__((ext_vector_type(4))) unsigned int;

__device__ __forceinline__ unsigned short f2bf(float f) {
    unsigned u = __builtin_bit_cast(unsigned, f);
    u += 0x7fffu + ((u >> 16) & 1u);   // RNE
    return (unsigned short)(u >> 16);
}
__device__ __forceinline__ float bf2f(unsigned short h) {
    return __builtin_bit_cast(float, (unsigned)h << 16);
}

__device__ __forceinline__ float wave_sum(float v) {
#pragma unroll
    for (int off = 32; off > 0; off >>= 1) v += __shfl_xor(v, off, 64);
    return v;
}
__device__ __forceinline__ float wave_max(float v) {
#pragma unroll
    for (int off = 32; off > 0; off >>= 1) v = fmaxf(v, __shfl_xor(v, off, 64));
    return v;
}

#define GLP(p)  ((const __attribute__((address_space(1))) void*)(p))
#define LDSP(p) ((__attribute__((address_space(3))) void*)(p))

// ---------- f32 -> bf16 bulk convert ----------
__global__ __launch_bounds__(256) void cvt_bf16(const float* __restrict__ in,
                                                unsigned short* __restrict__ out, long n8) {
    long i = (long)blockIdx.x * 256 + threadIdx.x;
    long stride = (long)gridDim.x * 256;
    for (; i < n8; i += stride) {
        const float4* p = (const float4*)(in + i * 8);
        float4 a = p[0], b = p[1];
        ushort8_t v;
        v[0] = f2bf(a.x); v[1] = f2bf(a.y); v[2] = f2bf(a.z); v[3] = f2bf(a.w);
        v[4] = f2bf(b.x); v[5] = f2bf(b.y); v[6] = f2bf(b.z); v[7] = f2bf(b.w);
        *(ushort8_t*)(out + i * 8) = v;
    }
}

// ---------- weight pack (transpose -> bf16, [N][K] row-major) ----------
__global__ void pack_w(const float* __restrict__ Wc, const float* __restrict__ Wi,
                       unsigned short* __restrict__ Wp) {
    int n = blockIdx.x, k = blockIdx.y * 256 + threadIdx.x;
    float v = (n < 768) ? Wc[(size_t)k * 768 + n] : Wi[(size_t)k * 768 + (n - 768)];
    Wp[(size_t)n * 2048 + k] = f2bf(v);
}

__global__ void pack_wq(const float* __restrict__ Wq, unsigned short* __restrict__ Wqt) {
    int n = blockIdx.x, k = blockIdx.y * 256 + threadIdx.x;
    Wqt[(size_t)n * 768 + k] = f2bf(Wq[(size_t)k * 768 + n]);
}

// ---------- 256x256 pipelined bf16 GEMM (R3 structure: BK=32, 4-deep) ----------
// C[M][N] = A[M][K] @ Bt[N][K]^T + bias.  8 waves (2Mx4N).
// T2 perm: 16B chunk (row r, slot s) -> phys chunk 4r + ((s + (r>>1))&3); zero conflicts (R3 PMC).
// OUTBF: 1 -> store bf16, 0 -> store f32.
template <int OUTBF>
__global__ __launch_bounds__(512, 1) void gemm8(
    const unsigned short* __restrict__ A, const unsigned short* __restrict__ Bt,
    const float* __restrict__ bias0, const float* __restrict__ bias1, int nsplit,
    void* __restrict__ Cv, int N, int K, int NTN)
{
    __shared__ unsigned short LA[4][8192];   // 4 bufs x 256 rows x 32 bf16 (16KB)
    __shared__ unsigned short LB[4][8192];
    const int tid = threadIdx.x, lane = tid & 63, wid = tid >> 6;

    int nwg = (int)gridDim.x, bid = (int)blockIdx.x;
    if ((nwg & 7) == 0) { int cpx = nwg >> 3; bid = (bid & 7) * cpx + (bid >> 3); }  // T1
    const int tn = bid % NTN, tm = bid / NTN;
    const size_t m0 = (size_t)tm * 256, n0 = (size_t)tn * 256;
    const int NT = K >> 5;

    const int wr = wid >> 2, wc = wid & 3;
    const int wm = wr * 128, wn = wc * 64;
    const int fr = lane & 15, fs = lane >> 4;

    // staging: thread covers chunks c0=tid, c1=tid+512 of each 1024-chunk tile
    const int c0 = tid, c1 = tid + 512;
    const int r0 = c0 >> 2, s0 = ((c0 & 3) - (r0 >> 1)) & 3;
    const int r1 = c1 >> 2, s1 = ((c1 & 3) - (r1 >> 1)) & 3;
    const unsigned short* gA0 = A + (m0 + r0) * K + s0 * 8;
    const unsigned short* gA1 = A + (m0 + r1) * K + s1 * 8;
    const unsigned short* gB0 = Bt + (n0 + r0) * K + s0 * 8;
    const unsigned short* gB1 = Bt + (n0 + r1) * K + s1 * 8;

    // fragment LDS element offsets (loop-invariant)
    int offA[8], offB[4];
#pragma unroll
    for (int mf = 0; mf < 8; ++mf) {
        int r = wm + mf * 16 + fr;
        offA[mf] = (4 * r + ((fs + (r >> 1)) & 3)) * 8;
    }
#pragma unroll
    for (int nf = 0; nf < 4; ++nf) {
        int r = wn + nf * 16 + fr;
        offB[nf] = (4 * r + ((fs + (r >> 1)) & 3)) * 8;
    }

    f32x4 acc[8][4];
#pragma unroll
    for (int i = 0; i < 8; ++i)
#pragma unroll
        for (int j = 0; j < 4; ++j) acc[i][j] = (f32x4){0.f, 0.f, 0.f, 0.f};

    // prologue: stage tiles 0,1,2
#pragma unroll
    for (int t = 0; t < 3; ++t) {
        if (t < NT) {
            __builtin_amdgcn_global_load_lds(GLP(gA0 + t * 32), LDSP(&LA[t][c0 * 8]), 16, 0, 0);
            __builtin_amdgcn_global_load_lds(GLP(gA1 + t * 32), LDSP(&LA[t][c1 * 8]), 16, 0, 0);
            __builtin_amdgcn_global_load_lds(GLP(gB0 + t * 32), LDSP(&LB[t][c0 * 8]), 16, 0, 0);
            __builtin_amdgcn_global_load_lds(GLP(gB1 + t * 32), LDSP(&LB[t][c1 * 8]), 16, 0, 0);
        }
    }

    for (int T = 0; T < NT; ++T) {
        const int buf = T & 3, pb = (T + 3) & 3;
        const int rem = NT - 1 - T;
        if (rem >= 2)      asm volatile("s_waitcnt vmcnt(8)" ::: "memory");
        else if (rem == 1) asm volatile("s_waitcnt vmcnt(4)" ::: "memory");
        else               asm volatile("s_waitcnt vmcnt(0)" ::: "memory");
        __builtin_amdgcn_s_barrier();           // all waves' tile-T loads landed
        __builtin_amdgcn_sched_barrier(0);

        bf16x8 av[4], bv[4];
        // ---- phase 1: M-half 0 x all N ----
#pragma unroll
        for (int mf = 0; mf < 4; ++mf) av[mf] = *(const bf16x8*)&LA[buf][offA[mf]];
#pragma unroll
        for (int nf = 0; nf < 4; ++nf) bv[nf] = *(const bf16x8*)&LB[buf][offB[nf]];
        if (T + 3 < NT) {
            __builtin_amdgcn_global_load_lds(GLP(gA0 + (size_t)(T + 3) * 32), LDSP(&LA[pb][c0 * 8]), 16, 0, 0);
            __builtin_amdgcn_global_load_lds(GLP(gA1 + (size_t)(T + 3) * 32), LDSP(&LA[pb][c1 * 8]), 16, 0, 0);
        }
        asm volatile("s_waitcnt lgkmcnt(0)" ::: "memory");
        __builtin_amdgcn_sched_barrier(0);      // rule #18
        __builtin_amdgcn_s_setprio(1);
#pragma unroll
        for (int mf = 0; mf < 4; ++mf)
#pragma unroll
            for (int nf = 0; nf < 4; ++nf)
                acc[mf][nf] = __builtin_amdgcn_mfma_f32_16x16x32_bf16(av[mf], bv[nf], acc[mf][nf], 0, 0, 0);
        __builtin_amdgcn_s_setprio(0);

        // ---- phase 2: M-half 1 x all N (B reused in regs) ----
#pragma unroll
        for (int mf = 0; mf < 4; ++mf) av[mf] = *(const bf16x8*)&LA[buf][offA[4 + mf]];
        if (T + 3 < NT) {
            __builtin_amdgcn_global_load_lds(GLP(gB0 + (size_t)(T + 3) * 32), LDSP(&LB[pb][c0 * 8]), 16, 0, 0);
            __builtin_amdgcn_global_load_lds(GLP(gB1 + (size_t)(T + 3) * 32), LDSP(&LB[pb][c1 * 8]), 16, 0, 0);
        }
        asm volatile("s_waitcnt lgkmcnt(0)" ::: "memory");
        __builtin_amdgcn_sched_barrier(0);
        __builtin_amdgcn_s_setprio(1);
#pragma unroll
        for (int mf = 0; mf < 4; ++mf)
#pragma unroll
            for (int nf = 0; nf < 4; ++nf)
                acc[4 + mf][nf] = __builtin_amdgcn_mfma_f32_16x16x32_bf16(av[mf], bv[nf], acc[4 + mf][nf], 0, 0, 0);
        __builtin_amdgcn_s_setprio(0);
    }

    // epilogue  (C/D layout: col = lane&15, row = (lane>>4)*4 + r)
#pragma unroll
    for (int nf = 0; nf < 4; ++nf) {
        int col = (int)n0 + wn + nf * 16 + fr;
        float bs = (col < nsplit) ? bias0[col] : bias1[col - nsplit];
#pragma unroll
        for (int mf = 0; mf < 8; ++mf) {
            size_t rowb = m0 + wm + mf * 16 + fs * 4;
#pragma unroll
            for (int r = 0; r < 4; ++r) {
                float v = acc[mf][nf][r] + bs;
                if (OUTBF) ((unsigned short*)Cv)[(rowb + r) * N + col] = f2bf(v);
                else       ((float*)Cv)[(rowb + r) * N + col] = v;
            }
        }
    }
}

// ---------- wm kernel: wm[b,t,n] = relu(LN_n( qf[b,t,:] . img_corr[b,n,:] )) ----------
// qf from bf16 Qbf (staged to LDS as f32); img_corr from bf16 imgCE.
__global__ __launch_bounds__(256) void wm_kernel(
    const unsigned short* __restrict__ qbf, const unsigned short* __restrict__ imgCE,
    const float* __restrict__ g1, const float* __restrict__ b1,
    float* __restrict__ wm_g)
{
    const int b = blockIdx.x, tid = threadIdx.x, lane = tid & 63, wid = tid >> 6;
    __shared__ float qf[14 * 768];
    __shared__ float wmr[14][100];

    const ushort8_t* src = (const ushort8_t*)(qbf + (size_t)b * 14 * 768);
    for (int i = tid; i < 14 * 768 / 8; i += 256) {
        ushort8_t v = src[i];
#pragma unroll
        for (int j = 0; j < 8; ++j) qf[i * 8 + j] = bf2f(v[j]);
    }
    __syncthreads();

    for (int n = wid; n < 100; n += 4) {
        const unsigned short* row = imgCE + ((size_t)b * 100 + n) * 1536;  // img_corr half
        float r[12];
#pragma unroll
        for (int j = 0; j < 12; ++j) r[j] = bf2f(row[lane + 64 * j]);
        for (int t = 0; t < 14; ++t) {
            const float* q = qf + t * 768;
            float s = 0.f;
#pragma unroll
            for (int j = 0; j < 12; ++j) s = fmaf(r[j], q[lane + 64 * j], s);
            s = wave_sum(s);
            if (lane == 0) wmr[t][n] = s;
        }
    }
    __syncthreads();

    for (int t = wid; t < 14; t += 4) {
        float x0 = wmr[t][lane];
        float x1 = (lane + 64 < 100) ? wmr[t][lane + 64] : 0.f;
        float s = wave_sum(x0 + x1);
        float q = wave_sum(x0 * x0 + x1 * x1);
        float mu = s * (1.f / 100.f);
        float var = q * (1.f / 100.f) - mu * mu;
        float rs = rsqrtf(var + 1e-3f);
        float* dst = wm_g + ((size_t)b * 14 + t) * 100;
        {
            float v = (x0 - mu) * rs * g1[lane] + b1[lane];
            dst[lane] = v > 0.f ? v : 0.f;
        }
        if (lane + 64 < 100) {
            float v = (x1 - mu) * rs * g1[lane + 64] + b1[lane + 64];
            dst[lane + 64] = v > 0.f ? v : 0.f;
        }
    }
}

// ---------- ques path ----------
__global__ __launch_bounds__(256) void ques_kernel(
    const float* __restrict__ qf_g, const float* __restrict__ qe_g,
    const unsigned short* __restrict__ imgCE, const float* __restrict__ wm_g,
    const float* __restrict__ g2, const float* __restrict__ b2,
    const float* __restrict__ g3, const float* __restrict__ b3,
    const float* __restrict__ wqa, const float* __restrict__ bqa,
    float* __restrict__ out_q)
{
    const int b = blockIdx.x, tid = threadIdx.x, lane = tid & 63, wid = tid >> 6;
    __shared__ float qe[14 * 768];
    __shared__ float wm[14 * 100];
    __shared__ float red[4][28];
    __shared__ float mu_s[14], rs_s[14], qa_s[14], qw_s[14];

    {
        const float4* src = (const float4*)(qe_g + (size_t)b * 14 * 768);
        for (int i = tid; i < 14 * 768 / 4; i += 256) ((float4*)qe)[i] = src[i];
        const float* ws = wm_g + (size_t)b * 1400;
        for (int i = tid; i < 1400; i += 256) wm[i] = ws[i];
    }
    __syncthreads();

    float a0[14], a1[14], a2[14];
#pragma unroll
    for (int t = 0; t < 14; ++t) { a0[t] = 0.f; a1[t] = 0.f; a2[t] = 0.f; }

    const unsigned short* ie_base = imgCE + (size_t)b * 100 * 1536 + 768;  // img_embed half
    for (int n = 0; n < 100; ++n) {
        const unsigned short* ie = ie_base + (size_t)n * 1536;
        float e0 = bf2f(ie[tid]), e1 = bf2f(ie[tid + 256]), e2 = bf2f(ie[tid + 512]);
#pragma unroll
        for (int t = 0; t < 14; ++t) {
            float w = wm[t * 100 + n];
            a0[t] = fmaf(w, e0, a0[t]); a1[t] = fmaf(w, e1, a1[t]); a2[t] = fmaf(w, e2, a2[t]);
        }
    }
#pragma unroll
    for (int t = 0; t < 14; ++t) {
        a0[t] += qe[t * 768 + tid];
        a1[t] += qe[t * 768 + tid + 256];
        a2[t] += qe[t * 768 + tid + 512];
    }
#pragma unroll
    for (int t = 0; t < 14; ++t) {
        float s = wave_sum(a0[t] + a1[t] + a2[t]);
        float q = wave_sum(a0[t] * a0[t] + a1[t] * a1[t] + a2[t] * a2[t]);
        if (lane == 0) { red[wid][t] = s; red[wid][14 + t] = q; }
    }
    __syncthreads();
    if (tid < 14) {
        float s = red[0][tid] + red[1][tid] + red[2][tid] + red[3][tid];
        float q = red[0][14 + tid] + red[1][14 + tid] + red[2][14 + tid] + red[3][14 + tid];
        float mu = s * (1.f / 768.f);
        float var = q * (1.f / 768.f) - mu * mu;
        mu_s[tid] = mu; rs_s[tid] = rsqrtf(var + 1e-3f);
    }
    __syncthreads();

    float ga = g2[tid], ba = b2[tid], gb = g2[tid + 256], bb = b2[tid + 256],
          gc = g2[tid + 512], bc_ = b2[tid + 512];
    float w0 = wqa[tid], w1 = wqa[tid + 256], w2 = wqa[tid + 512];
#pragma unroll
    for (int t = 0; t < 14; ++t) {
        float mu = mu_s[t], rs = rs_s[t];
        float v0 = fmaxf((a0[t] - mu) * rs * ga + ba, 0.f);
        float v1 = fmaxf((a1[t] - mu) * rs * gb + bb, 0.f);
        float v2 = fmaxf((a2[t] - mu) * rs * gc + bc_, 0.f);
        float p = wave_sum(v0 * w0 + v1 * w1 + v2 * w2);
        if (lane == 0) red[wid][t] = p;
    }
    __syncthreads();
    if (tid < 14) qa_s[tid] = red[0][tid] + red[1][tid] + red[2][tid] + red[3][tid] + bqa[0];
    __syncthreads();
    if (tid == 0) {
        float s = 0.f;
        for (int t = 0; t < 14; ++t) s += qa_s[t];
        float mu = s * (1.f / 14.f);
        float q = 0.f;
        for (int t = 0; t < 14; ++t) { float d = qa_s[t] - mu; q += d * d; }
        float rs = rsqrtf(q * (1.f / 14.f) + 1e-3f);
        float e[14], mx = -1e30f;
        for (int t = 0; t < 14; ++t) { e[t] = (qa_s[t] - mu) * rs * g3[t] + b3[t]; mx = fmaxf(mx, e[t]); }
        float se = 0.f;
        for (int t = 0; t < 14; ++t) { e[t] = expf(e[t] - mx); se += e[t]; }
        float inv = 1.f / se;
        for (int t = 0; t < 14; ++t) qw_s[t] = e[t] * inv;
    }
    __syncthreads();

    const float* qf = qf_g + (size_t)b * 14 * 768;
#pragma unroll
    for (int c = 0; c < 3; ++c) {
        int h = tid + c * 256;
        float o = 0.f;
#pragma unroll
        for (int t = 0; t < 14; ++t) o = fmaf(qw_s[t], qf[t * 768 + h], o);
        out_q[(size_t)b * 768 + h] = o;
    }
}

// ---------- img path ----------
__global__ __launch_bounds__(256) void img_kernel(
    const unsigned short* __restrict__ imf_bf, const float* __restrict__ qe_g,
    const unsigned short* __restrict__ imgCE, const float* __restrict__ wm_g,
    const float* __restrict__ g4, const float* __restrict__ b4,
    const float* __restrict__ g5, const float* __restrict__ b5,
    const float* __restrict__ wia, const float* __restrict__ bia,
    float* __restrict__ out_i)
{
    const int b = blockIdx.x, tid = threadIdx.x, lane = tid & 63, wid = tid >> 6;
    __shared__ float qe[14 * 768];
    __shared__ float wm[14 * 100];
    __shared__ float red[4][20];
    __shared__ float mu_s[10], rs_s[10];
    __shared__ float ia_s[100], iw_s[100];

    {
        const float4* src = (const float4*)(qe_g + (size_t)b * 14 * 768);
        for (int i = tid; i < 14 * 768 / 4; i += 256) ((float4*)qe)[i] = src[i];
        const float* ws = wm_g + (size_t)b * 1400;
        for (int i = tid; i < 1400; i += 256) wm[i] = ws[i];
    }
    __syncthreads();

    float g4a = g4[tid], b4a = b4[tid], g4b = g4[tid + 256], b4b = b4[tid + 256],
          g4c = g4[tid + 512], b4c = b4[tid + 512];
    float wa = wia[tid], wb = wia[tid + 256], wc_ = wia[tid + 512];

    for (int g = 0; g < 10; ++g) {
        float t0[10], t1[10], t2[10];
#pragma unroll
        for (int i = 0; i < 10; ++i) { t0[i] = 0.f; t1[i] = 0.f; t2[i] = 0.f; }
#pragma unroll
        for (int t = 0; t < 14; ++t) {
            float q0 = qe[t * 768 + tid], q1 = qe[t * 768 + tid + 256], q2 = qe[t * 768 + tid + 512];
#pragma unroll
            for (int i = 0; i < 10; ++i) {
                float w = wm[t * 100 + g * 10 + i];
                t0[i] = fmaf(w, q0, t0[i]); t1[i] = fmaf(w, q1, t1[i]); t2[i] = fmaf(w, q2, t2[i]);
            }
        }
#pragma unroll
        for (int i = 0; i < 10; ++i) {
            const unsigned short* ie = imgCE + ((size_t)b * 100 + g * 10 + i) * 1536 + 768;
            t0[i] += bf2f(ie[tid]); t1[i] += bf2f(ie[tid + 256]); t2[i] += bf2f(ie[tid + 512]);
            float s = wave_sum(t0[i] + t1[i] + t2[i]);
            float q = wave_sum(t0[i] * t0[i] + t1[i] * t1[i] + t2[i] * t2[i]);
            if (lane == 0) { red[wid][i] = s; red[wid][10 + i] = q; }
        }
        __syncthreads();
        if (tid < 10) {
            float s = red[0][tid] + red[1][tid] + red[2][tid] + red[3][tid];
            float q = red[0][10 + tid] + red[1][10 + tid] + red[2][10 + tid] + red[3][10 + tid];
            float mu = s * (1.f / 768.f);
            float var = q * (1.f / 768.f) - mu * mu;
            mu_s[tid] = mu; rs_s[tid] = rsqrtf(var + 1e-3f);
        }
        __syncthreads();
#pragma unroll
        for (int i = 0; i < 10; ++i) {
            float mu = mu_s[i], rs = rs_s[i];
            float v0 = fmaxf((t0[i] - mu) * rs * g4a + b4a, 0.f);
            float v1 = fmaxf((t1[i] - mu) * rs * g4b + b4b, 0.f);
            float v2 = fmaxf((t2[i] - mu) * rs * g4c + b4c, 0.f);
            float p = wave_sum(v0 * wa + v1 * wb + v2 * wc_);
            if (lane == 0) red[wid][i] = p;
        }
        __syncthreads();
        if (tid < 10) ia_s[g * 10 + tid] = red[0][tid] + red[1][tid] + red[2][tid] + red[3][tid] + bia[0];
        __syncthreads();
    }

    if (wid == 0) {
        float x0 = ia_s[lane];
        float x1 = (lane + 64 < 100) ? ia_s[lane + 64] : 0.f;
        float s = wave_sum(x0 + x1);
        float q = wave_sum(x0 * x0 + x1 * x1);
        float mu = s * 0.01f;
        float var = q * 0.01f - mu * mu;
        float rs = rsqrtf(var + 1e-3f);
        float v0 = (x0 - mu) * rs * g5[lane] + b5[lane];
        float v1 = (lane + 64 < 100) ? (x1 - mu) * rs * g5[lane + 64] + b5[lane + 64] : -1e30f;
        float mx = wave_max(fmaxf(v0, v1));
        float e0 = expf(v0 - mx);
        float e1 = (lane + 64 < 100) ? expf(v1 - mx) : 0.f;
        float se = wave_sum(e0 + e1);
        float inv = 1.f / se;
        iw_s[lane] = e0 * inv;
        if (lane + 64 < 100) iw_s[lane + 64] = e1 * inv;
    }
    __syncthreads();

    // img_atten_feat = sum_n iw[n] * img_feat[b,n,:]   (bf16 reads)
    const unsigned short* imf = imf_bf + (size_t)b * 100 * 2048;
    float acc8[8];
#pragma unroll
    for (int j = 0; j < 8; ++j) acc8[j] = 0.f;
    for (int n = 0; n < 100; ++n) {
        ushort8_t v = *(const ushort8_t*)(imf + (size_t)n * 2048 + tid * 8);
        float w = iw_s[n];
#pragma unroll
        for (int j = 0; j < 8; ++j) acc8[j] = fmaf(w, bf2f(v[j]), acc8[j]);
    }
    float4* dst = (float4*)(out_i + (size_t)b * 2048);
    float4 oA = {acc8[0], acc8[1], acc8[2], acc8[3]};
    float4 oB = {acc8[4], acc8[5], acc8[6], acc8[7]};
    dst[tid * 2] = oA; dst[tid * 2 + 1] = oB;
}

// ---------- launch ----------
extern "C" void kernel_launch(void* const* d_in, const int* in_sizes, int n_in,
                              void* d_out, int out_size, void* d_ws, size_t ws_size,
                              hipStream_t stream)
{
    const float* img_feat = (const float*)d_in[0];
    const float* ques_feat = (const float*)d_in[1];
    const float* Wc = (const float*)d_in[2];
    const float* bc = (const float*)d_in[3];
    const float* Wq = (const float*)d_in[4];
    const float* bq = (const float*)d_in[5];
    const float* Wi = (const float*)d_in[6];
    const float* bi = (const float*)d_in[7];
    const float* wqa = (const float*)d_in[8];
    const float* bqa = (const float*)d_in[9];
    const float* wia = (const float*)d_in[10];
    const float* bia = (const float*)d_in[11];
    const float* g1 = (const float*)d_in[12]; const float* b1 = (const float*)d_in[13];
    const float* g2 = (const float*)d_in[14]; const float* b2 = (const float*)d_in[15];
    const float* g3 = (const float*)d_in[16]; const float* b3 = (const float*)d_in[17];
    const float* g4 = (const float*)d_in[18]; const float* b4 = (const float*)d_in[19];
    const float* g5 = (const float*)d_in[20]; const float* b5 = (const float*)d_in[21];

    // workspace layout (bytes)
    const size_t SZ_WP   = 1536u * 2048u * 2u;        //   6,291,456
    const size_t SZ_WQT  = 768u * 768u * 2u;          //   1,179,648
    const size_t SZ_IMG  = 51200ull * 1536u * 2u;     // 157,286,400 (bf16 now)
    const size_t SZ_QE   = 7168u * 768u * 4u;         //  22,020,096 (f32)
    const size_t SZ_WM   = 512u * 1400u * 4u;         //   2,867,200
    const size_t SZ_ABF  = 51200ull * 2048u * 2u;     // 209,715,200
    const size_t SZ_QBF  = 7168u * 768u * 2u;         //  11,010,048

    const size_t OFF_WP  = 0;
    const size_t OFF_WQT = OFF_WP + SZ_WP;
    const size_t OFF_IMG = OFF_WQT + SZ_WQT;
    const size_t OFF_QE  = OFF_IMG + SZ_IMG;
    const size_t OFF_WM  = OFF_QE + SZ_QE;
    const size_t OFF_ABF = OFF_WM + SZ_WM;
    const size_t OFF_QBF = OFF_ABF + SZ_ABF;
    const size_t NEED    = OFF_QBF + SZ_QBF;          // ~410 MB
    if (ws_size < NEED) return;

    char* ws = (char*)d_ws;
    unsigned short* Wp    = (unsigned short*)(ws + OFF_WP);
    unsigned short* Wqt   = (unsigned short*)(ws + OFF_WQT);
    unsigned short* imgCE = (unsigned short*)(ws + OFF_IMG);
    float*          qe    = (float*)(ws + OFF_QE);
    float*          wm    = (float*)(ws + OFF_WM);
    unsigned short* Abf   = (unsigned short*)(ws + OFF_ABF);
    unsigned short* Qbf   = (unsigned short*)(ws + OFF_QBF);

    float* out_img = (float*)d_out;                   // [512][2048]
    float* out_q   = (float*)d_out + 512 * 2048;      // [512][768]

    hipLaunchKernelGGL(pack_w,  dim3(1536, 8), dim3(256), 0, stream, Wc, Wi, Wp);
    hipLaunchKernelGGL(pack_wq, dim3(768, 3),  dim3(256), 0, stream, Wq, Wqt);
    hipLaunchKernelGGL(cvt_bf16, dim3(2048), dim3(256), 0, stream,
                       img_feat, Abf, (long)(51200ull * 2048u / 8u));
    hipLaunchKernelGGL(cvt_bf16, dim3(1024), dim3(256), 0, stream,
                       ques_feat, Qbf, (long)(7168u * 768u / 8u));

    // imgCE(bf16) = img_feat @ [Wc|Wi] + [bc|bi]   (M=51200, N=1536, K=2048)
    hipLaunchKernelGGL(HIP_KERNEL_NAME(gemm8<1>), dim3(1200), dim3(512), 0, stream,
                       Abf, Wp, bc, bi, 768, (void*)imgCE, 1536, 2048, 6);
    // qe(f32) = ques_feat @ Wq + bq                (M=7168, N=768, K=768)
    hipLaunchKernelGGL(HIP_KERNEL_NAME(gemm8<0>), dim3(84), dim3(512), 0, stream,
                       Qbf, Wqt, bq, bq, 768, (void*)qe, 768, 768, 3);

    hipLaunchKernelGGL(wm_kernel, dim3(512), dim3(256), 0, stream,
                       Qbf, imgCE, g1, b1, wm);
    hipLaunchKernelGGL(ques_kernel, dim3(512), dim3(256), 0, stream,
                       ques_feat, qe, imgCE, wm, g2, b2, g3, b3, wqa, bqa, out_q);
    hipLaunchKernelGGL(img_kernel, dim3(512), dim3(256), 0, stream,
                       Abf, qe, imgCE, wm, g4, b4, g5, b5, wia, bia, out_img);
}

// Round 6
// 798.844 us; speedup vs baseline: 1.1314x; 1.0140x over previous
//
#include <hip/hip_runtime.h>

// ---------- types & helpers ----------
using f32x4     = __attribute__((ext_vector_type(4))) float;
using bf16x8    = __attribute__((ext_vector_type(8))) short;
using ushort8_t = __attribute__((ext_vector_type(8))) unsigned short;

__device__ __forceinline__ unsigned short f2bf(float f) {
    unsigned u = __builtin_bit_cast(unsigned, f);
    u += 0x7fffu + ((u >> 16) & 1u);   // RNE
    return (unsigned short)(u >> 16);
}
__device__ __forceinline__ float bf2f(unsigned short h) {
    return __builtin_bit_cast(float, (unsigned)h << 16);
}

__device__ __forceinline__ float wave_sum(float v) {
#pragma unroll
    for (int off = 32; off > 0; off >>= 1) v += __shfl_xor(v, off, 64);
    return v;
}
__device__ __forceinline__ float wave_max(float v) {
#pragma unroll
    for (int off = 32; off > 0; off >>= 1) v = fmaxf(v, __shfl_xor(v, off, 64));
    return v;
}

#define GLP(p)  ((const __attribute__((address_space(1))) void*)(p))
#define LDSP(p) ((__attribute__((address_space(3))) void*)(p))

// ---------- f32 -> bf16 bulk convert ----------
__global__ __launch_bounds__(256) void cvt_bf16(const float* __restrict__ in,
                                                unsigned short* __restrict__ out, long n8) {
    long i = (long)blockIdx.x * 256 + threadIdx.x;
    long stride = (long)gridDim.x * 256;
    for (; i < n8; i += stride) {
        const float4* p = (const float4*)(in + i * 8);
        float4 a = p[0], b = p[1];
        ushort8_t v;
        v[0] = f2bf(a.x); v[1] = f2bf(a.y); v[2] = f2bf(a.z); v[3] = f2bf(a.w);
        v[4] = f2bf(b.x); v[5] = f2bf(b.y); v[6] = f2bf(b.z); v[7] = f2bf(b.w);
        *(ushort8_t*)(out + i * 8) = v;
    }
}

// ---------- weight pack (transpose -> bf16, [N][K] row-major) ----------
__global__ void pack_w(const float* __restrict__ Wc, const float* __restrict__ Wi,
                       unsigned short* __restrict__ Wp) {
    int n = blockIdx.x, k = blockIdx.y * 256 + threadIdx.x;
    float v = (n < 768) ? Wc[(size_t)k * 768 + n] : Wi[(size_t)k * 768 + (n - 768)];
    Wp[(size_t)n * 2048 + k] = f2bf(v);
}

__global__ void pack_wq(const float* __restrict__ Wq, unsigned short* __restrict__ Wqt) {
    int n = blockIdx.x, k = blockIdx.y * 256 + threadIdx.x;
    Wqt[(size_t)n * 768 + k] = f2bf(Wq[(size_t)k * 768 + n]);
}

// ---------- 256x256 bf16 GEMM, 8-phase schedule (m201 port) ----------
// C[M][N] = A[M][K] @ Bt[N][K]^T + bias.  BK=64, 2 K-tiles/iteration, 8 phases.
// 8 waves: wr=wid>>2 (M-half), wc=wid&3 (64-col slice). Per-wave out 128x64.
// LDS: [dbuf 2][half 2][128x64] per operand = 128 KiB.  tile t -> dbuf t&1.
// Swizzle: 16B chunk (row r, slot s=k/8) -> phys chunk r*8 + ((s+r)&7); ks=1 read = ^32 elems.
// Stage plan per iteration i (t0=2i buf0, t1=2i+1 buf1), one half-tile (2 gload_lds) per phase:
//   ph1:A0(t1) ph2:A1(t1) ph3:B0(t0+2) ph4:B1(t0+2)+gate(t1,vmcnt4)
//   ph5:A0(t0+2) ph6:A1(t0+2) ph7:B0(t1+2) ph8:B1(t1+2)+gate(t0+2,vmcnt4)
// Hazard ledger: every stage lands >=2 barriers after the last ds_read of the region it
// overwrites (B(t) reads end ph2/ph6, A(t) reads end ph3/ph7). Gates drain exactly the
// 2 stages issued after the gated tile's last load. Never vmcnt(0) mid-loop.
template <int OUTBF>
__global__ __launch_bounds__(512, 1) void gemm8(
    const unsigned short* __restrict__ A, const unsigned short* __restrict__ Bt,
    const float* __restrict__ bias0, const float* __restrict__ bias1, int nsplit,
    void* __restrict__ Cv, int N, int K, int NTN)
{
    __shared__ unsigned short LA[2][2][8192];
    __shared__ unsigned short LB[2][2][8192];
    const int tid = threadIdx.x, lane = tid & 63, wid = tid >> 6;

    int nwg = (int)gridDim.x, bid = (int)blockIdx.x;
    if ((nwg & 7) == 0) { int cpx = nwg >> 3; bid = (bid & 7) * cpx + (bid >> 3); }  // T1
    const int tn = bid % NTN, tm = bid / NTN;
    const size_t m0 = (size_t)tm * 256, n0 = (size_t)tn * 256;
    const int NT = K >> 6;            // BK=64 tiles (even for K=2048/768)
    const int NIT = NT >> 1;

    const int wr = wid >> 2, wc = wid & 3;
    const int hb = wc >> 1;
    const int fr = lane & 15, fs = lane >> 4;

    // staging: half-tile = 128 rows x 64 bf16 = 1024 x 16B chunks; thread covers c=tid, tid+512
    const int r0 = tid >> 3, s0 = ((tid & 7) - r0) & 7;
    const int r1 = r0 + 64,  s1 = ((tid & 7) - r1) & 7;
    const unsigned short* pA[2][2];
    const unsigned short* pB[2][2];
#pragma unroll
    for (int h = 0; h < 2; ++h) {
        pA[h][0] = A  + (m0 + h * 128 + r0) * K + s0 * 8;
        pA[h][1] = A  + (m0 + h * 128 + r1) * K + s1 * 8;
        pB[h][0] = Bt + (n0 + h * 128 + r0) * K + s0 * 8;
        pB[h][1] = Bt + (n0 + h * 128 + r1) * K + s1 * 8;
    }
    const int d0 = tid * 8, d1 = (tid + 512) * 8;

#define STG_A(h, t, B_) do { \
    __builtin_amdgcn_global_load_lds(GLP(pA[h][0] + (size_t)(t) * 64), LDSP(&LA[B_][h][d0]), 16, 0, 0); \
    __builtin_amdgcn_global_load_lds(GLP(pA[h][1] + (size_t)(t) * 64), LDSP(&LA[B_][h][d1]), 16, 0, 0); \
} while (0)
#define STG_B(h, t, B_) do { \
    __builtin_amdgcn_global_load_lds(GLP(pB[h][0] + (size_t)(t) * 64), LDSP(&LB[B_][h][d0]), 16, 0, 0); \
    __builtin_amdgcn_global_load_lds(GLP(pB[h][1] + (size_t)(t) * 64), LDSP(&LB[B_][h][d1]), 16, 0, 0); \
} while (0)

    // fragment LDS element offsets (ks=0); ks=1 -> ^32
    int offA[2][4], offB[2][2];
#pragma unroll
    for (int mq = 0; mq < 2; ++mq)
#pragma unroll
        for (int mfl = 0; mfl < 4; ++mfl) {
            int r = mq * 64 + mfl * 16 + fr;
            offA[mq][mfl] = r * 64 + ((fs + r) & 7) * 8;
        }
#pragma unroll
    for (int nq = 0; nq < 2; ++nq)
#pragma unroll
        for (int nfl = 0; nfl < 2; ++nfl) {
            int r = (wc & 1) * 64 + nq * 32 + nfl * 16 + fr;
            offB[nq][nfl] = r * 64 + ((fs + r) & 7) * 8;
        }

#define LDA_SUB(B_, mq) do { \
    _Pragma("unroll") \
    for (int mfl = 0; mfl < 4; ++mfl) { \
        av[mfl][0] = *(const bf16x8*)&LA[B_][wr][offA[mq][mfl]]; \
        av[mfl][1] = *(const bf16x8*)&LA[B_][wr][offA[mq][mfl] ^ 32]; \
    } } while (0)
#define LDB_SUB(B_, nq, bv) do { \
    _Pragma("unroll") \
    for (int nfl = 0; nfl < 2; ++nfl) { \
        bv[nfl][0] = *(const bf16x8*)&LB[B_][hb][offB[nq][nfl]]; \
        bv[nfl][1] = *(const bf16x8*)&LB[B_][hb][offB[nq][nfl] ^ 32]; \
    } } while (0)
#define MMA_Q(mq, nq, bv) do { \
    _Pragma("unroll") \
    for (int ks = 0; ks < 2; ++ks) \
    _Pragma("unroll") \
    for (int mfl = 0; mfl < 4; ++mfl) \
    _Pragma("unroll") \
    for (int nfl = 0; nfl < 2; ++nfl) \
        acc[mq * 4 + mfl][nq * 2 + nfl] = __builtin_amdgcn_mfma_f32_16x16x32_bf16( \
            av[mfl][ks], bv[nfl][ks], acc[mq * 4 + mfl][nq * 2 + nfl], 0, 0, 0); \
    } while (0)
#define BAR  __builtin_amdgcn_s_barrier()
#define SCB  __builtin_amdgcn_sched_barrier(0)
#define LGKM0 do { asm volatile("s_waitcnt lgkmcnt(0)" ::: "memory"); SCB; } while (0)
#define PRIO1 __builtin_amdgcn_s_setprio(1)
#define PRIO0 __builtin_amdgcn_s_setprio(0)

    f32x4 acc[8][4];
#pragma unroll
    for (int i = 0; i < 8; ++i)
#pragma unroll
        for (int j = 0; j < 4; ++j) acc[i][j] = (f32x4){0.f, 0.f, 0.f, 0.f};

    // prologue: tile0 all halves (buf0) + tile1 B halves (buf1)
    STG_A(0, 0, 0); STG_A(1, 0, 0); STG_B(0, 0, 0); STG_B(1, 0, 0);
    STG_B(0, 1, 1); STG_B(1, 1, 1);
    asm volatile("s_waitcnt vmcnt(4)" ::: "memory");   // tile0 landed; tile1-B in flight
    SCB; BAR;

    for (int i = 0; i < NIT; ++i) {
        const int t0 = 2 * i, t1 = 2 * i + 1;
        const bool st = (t0 + 2 < NT);
        bf16x8 av[4][2], bv0[2][2], bv1[2][2];

        // ---- ph1 (t0: mq0,nq0) ----
        LDA_SUB(0, 0); LDB_SUB(0, 0, bv0);
        STG_A(0, t1, 1);
        SCB; BAR; LGKM0;
        PRIO1; MMA_Q(0, 0, bv0); PRIO0;
        BAR;
        // ---- ph2 (t0: mq0,nq1) ----
        LDB_SUB(0, 1, bv1);
        STG_A(1, t1, 1);
        SCB; BAR; LGKM0;
        PRIO1; MMA_Q(0, 1, bv1); PRIO0;
        BAR;
        // ---- ph3 (t0: mq1,nq1) ----
        LDA_SUB(0, 1);
        if (st) STG_B(0, t0 + 2, 0);
        SCB; BAR; LGKM0;
        PRIO1; MMA_Q(1, 1, bv1); PRIO0;
        BAR;
        // ---- ph4 (t0: mq1,nq0) + gate t1 ----
        if (st) STG_B(1, t0 + 2, 0);
        SCB; BAR;
        PRIO1; MMA_Q(1, 0, bv0); PRIO0;
        if (st) asm volatile("s_waitcnt vmcnt(4)" ::: "memory");
        else    asm volatile("s_waitcnt vmcnt(0)" ::: "memory");
        SCB; BAR;
        // ---- ph5 (t1: mq0,nq0) ----
        LDA_SUB(1, 0); LDB_SUB(1, 0, bv0);
        if (st) STG_A(0, t0 + 2, 0);
        SCB; BAR; LGKM0;
        PRIO1; MMA_Q(0, 0, bv0); PRIO0;
        BAR;
        // ---- ph6 (t1: mq0,nq1) ----
        LDB_SUB(1, 1, bv1);
        if (st) STG_A(1, t0 + 2, 0);
        SCB; BAR; LGKM0;
        PRIO1; MMA_Q(0, 1, bv1); PRIO0;
        BAR;
        // ---- ph7 (t1: mq1,nq1) ----
        LDA_SUB(1, 1);
        if (st) STG_B(0, t1 + 2, 1);
        SCB; BAR; LGKM0;
        PRIO1; MMA_Q(1, 1, bv1); PRIO0;
        BAR;
        // ---- ph8 (t1: mq1,nq0) + gate next t0 ----
        if (st) STG_B(1, t1 + 2, 1);
        SCB; BAR;
        PRIO1; MMA_Q(1, 0, bv0); PRIO0;
        if (st) asm volatile("s_waitcnt vmcnt(4)" ::: "memory");
        else    asm volatile("s_waitcnt vmcnt(0)" ::: "memory");
        SCB; BAR;
    }

#undef STG_A
#undef STG_B
#undef LDA_SUB
#undef LDB_SUB
#undef MMA_Q
#undef BAR
#undef SCB
#undef LGKM0
#undef PRIO1
#undef PRIO0

    // epilogue  (C/D layout: col = lane&15, row = (lane>>4)*4 + r)
    const int wm = wr * 128, wn = wc * 64;
#pragma unroll
    for (int nf = 0; nf < 4; ++nf) {
        int col = (int)n0 + wn + nf * 16 + fr;
        float bs = (col < nsplit) ? bias0[col] : bias1[col - nsplit];
#pragma unroll
        for (int mf = 0; mf < 8; ++mf) {
            size_t rowb = m0 + wm + mf * 16 + fs * 4;
#pragma unroll
            for (int r = 0; r < 4; ++r) {
                float v = acc[mf][nf][r] + bs;
                if (OUTBF) ((unsigned short*)Cv)[(rowb + r) * N + col] = f2bf(v);
                else       ((float*)Cv)[(rowb + r) * N + col] = v;
            }
        }
    }
}

// ---------- wm kernel: wm[b,t,n] = relu(LN_n( qf[b,t,:] . img_corr[b,n,:] )) ----------
__global__ __launch_bounds__(256) void wm_kernel(
    const unsigned short* __restrict__ qbf, const unsigned short* __restrict__ imgCE,
    const float* __restrict__ g1, const float* __restrict__ b1,
    float* __restrict__ wm_g)
{
    const int b = blockIdx.x, tid = threadIdx.x, lane = tid & 63, wid = tid >> 6;
    __shared__ float qf[14 * 768];
    __shared__ float wmr[14][100];

    const ushort8_t* src = (const ushort8_t*)(qbf + (size_t)b * 14 * 768);
    for (int i = tid; i < 14 * 768 / 8; i += 256) {
        ushort8_t v = src[i];
#pragma unroll
        for (int j = 0; j < 8; ++j) qf[i * 8 + j] = bf2f(v[j]);
    }
    __syncthreads();

    for (int n = wid; n < 100; n += 4) {
        const unsigned short* row = imgCE + ((size_t)b * 100 + n) * 1536;  // img_corr half
        float r[12];
#pragma unroll
        for (int j = 0; j < 12; ++j) r[j] = bf2f(row[lane + 64 * j]);
        for (int t = 0; t < 14; ++t) {
            const float* q = qf + t * 768;
            float s = 0.f;
#pragma unroll
            for (int j = 0; j < 12; ++j) s = fmaf(r[j], q[lane + 64 * j], s);
            s = wave_sum(s);
            if (lane == 0) wmr[t][n] = s;
        }
    }
    __syncthreads();

    for (int t = wid; t < 14; t += 4) {
        float x0 = wmr[t][lane];
        float x1 = (lane + 64 < 100) ? wmr[t][lane + 64] : 0.f;
        float s = wave_sum(x0 + x1);
        float q = wave_sum(x0 * x0 + x1 * x1);
        float mu = s * (1.f / 100.f);
        float var = q * (1.f / 100.f) - mu * mu;
        float rs = rsqrtf(var + 1e-3f);
        float* dst = wm_g + ((size_t)b * 14 + t) * 100;
        {
            float v = (x0 - mu) * rs * g1[lane] + b1[lane];
            dst[lane] = v > 0.f ? v : 0.f;
        }
        if (lane + 64 < 100) {
            float v = (x1 - mu) * rs * g1[lane + 64] + b1[lane + 64];
            dst[lane + 64] = v > 0.f ? v : 0.f;
        }
    }
}

// ---------- ques path ----------
__global__ __launch_bounds__(256) void ques_kernel(
    const float* __restrict__ qf_g, const float* __restrict__ qe_g,
    const unsigned short* __restrict__ imgCE, const float* __restrict__ wm_g,
    const float* __restrict__ g2, const float* __restrict__ b2,
    const float* __restrict__ g3, const float* __restrict__ b3,
    const float* __restrict__ wqa, const float* __restrict__ bqa,
    float* __restrict__ out_q)
{
    const int b = blockIdx.x, tid = threadIdx.x, lane = tid & 63, wid = tid >> 6;
    __shared__ float qe[14 * 768];
    __shared__ float wm[14 * 100];
    __shared__ float red[4][28];
    __shared__ float mu_s[14], rs_s[14], qa_s[14], qw_s[14];

    {
        const float4* src = (const float4*)(qe_g + (size_t)b * 14 * 768);
        for (int i = tid; i < 14 * 768 / 4; i += 256) ((float4*)qe)[i] = src[i];
        const float* ws = wm_g + (size_t)b * 1400;
        for (int i = tid; i < 1400; i += 256) wm[i] = ws[i];
    }
    __syncthreads();

    float a0[14], a1[14], a2[14];
#pragma unroll
    for (int t = 0; t < 14; ++t) { a0[t] = 0.f; a1[t] = 0.f; a2[t] = 0.f; }

    const unsigned short* ie_base = imgCE + (size_t)b * 100 * 1536 + 768;  // img_embed half
    for (int n = 0; n < 100; ++n) {
        const unsigned short* ie = ie_base + (size_t)n * 1536;
        float e0 = bf2f(ie[tid]), e1 = bf2f(ie[tid + 256]), e2 = bf2f(ie[tid + 512]);
#pragma unroll
        for (int t = 0; t < 14; ++t) {
            float w = wm[t * 100 + n];
            a0[t] = fmaf(w, e0, a0[t]); a1[t] = fmaf(w, e1, a1[t]); a2[t] = fmaf(w, e2, a2[t]);
        }
    }
#pragma unroll
    for (int t = 0; t < 14; ++t) {
        a0[t] += qe[t * 768 + tid];
        a1[t] += qe[t * 768 + tid + 256];
        a2[t] += qe[t * 768 + tid + 512];
    }
#pragma unroll
    for (int t = 0; t < 14; ++t) {
        float s = wave_sum(a0[t] + a1[t] + a2[t]);
        float q = wave_sum(a0[t] * a0[t] + a1[t] * a1[t] + a2[t] * a2[t]);
        if (lane == 0) { red[wid][t] = s; red[wid][14 + t] = q; }
    }
    __syncthreads();
    if (tid < 14) {
        float s = red[0][tid] + red[1][tid] + red[2][tid] + red[3][tid];
        float q = red[0][14 + tid] + red[1][14 + tid] + red[2][14 + tid] + red[3][14 + tid];
        float mu = s * (1.f / 768.f);
        float var = q * (1.f / 768.f) - mu * mu;
        mu_s[tid] = mu; rs_s[tid] = rsqrtf(var + 1e-3f);
    }
    __syncthreads();

    float ga = g2[tid], ba = b2[tid], gb = g2[tid + 256], bb = b2[tid + 256],
          gc = g2[tid + 512], bc_ = b2[tid + 512];
    float w0 = wqa[tid], w1 = wqa[tid + 256], w2 = wqa[tid + 512];
#pragma unroll
    for (int t = 0; t < 14; ++t) {
        float mu = mu_s[t], rs = rs_s[t];
        float v0 = fmaxf((a0[t] - mu) * rs * ga + ba, 0.f);
        float v1 = fmaxf((a1[t] - mu) * rs * gb + bb, 0.f);
        float v2 = fmaxf((a2[t] - mu) * rs * gc + bc_, 0.f);
        float p = wave_sum(v0 * w0 + v1 * w1 + v2 * w2);
        if (lane == 0) red[wid][t] = p;
    }
    __syncthreads();
    if (tid < 14) qa_s[tid] = red[0][tid] + red[1][tid] + red[2][tid] + red[3][tid] + bqa[0];
    __syncthreads();
    if (tid == 0) {
        float s = 0.f;
        for (int t = 0; t < 14; ++t) s += qa_s[t];
        float mu = s * (1.f / 14.f);
        float q = 0.f;
        for (int t = 0; t < 14; ++t) { float d = qa_s[t] - mu; q += d * d; }
        float rs = rsqrtf(q * (1.f / 14.f) + 1e-3f);
        float e[14], mx = -1e30f;
        for (int t = 0; t < 14; ++t) { e[t] = (qa_s[t] - mu) * rs * g3[t] + b3[t]; mx = fmaxf(mx, e[t]); }
        float se = 0.f;
        for (int t = 0; t < 14; ++t) { e[t] = expf(e[t] - mx); se += e[t]; }
        float inv = 1.f / se;
        for (int t = 0; t < 14; ++t) qw_s[t] = e[t] * inv;
    }
    __syncthreads();

    const float* qf = qf_g + (size_t)b * 14 * 768;
#pragma unroll
    for (int c = 0; c < 3; ++c) {
        int h = tid + c * 256;
        float o = 0.f;
#pragma unroll
        for (int t = 0; t < 14; ++t) o = fmaf(qw_s[t], qf[t * 768 + h], o);
        out_q[(size_t)b * 768 + h] = o;
    }
}

// ---------- img path ----------
__global__ __launch_bounds__(256) void img_kernel(
    const unsigned short* __restrict__ imf_bf, const float* __restrict__ qe_g,
    const unsigned short* __restrict__ imgCE, const float* __restrict__ wm_g,
    const float* __restrict__ g4, const float* __restrict__ b4,
    const float* __restrict__ g5, const float* __restrict__ b5,
    const float* __restrict__ wia, const float* __restrict__ bia,
    float* __restrict__ out_i)
{
    const int b = blockIdx.x, tid = threadIdx.x, lane = tid & 63, wid = tid >> 6;
    __shared__ float qe[14 * 768];
    __shared__ float wm[14 * 100];
    __shared__ float red[4][20];
    __shared__ float mu_s[10], rs_s[10];
    __shared__ float ia_s[100], iw_s[100];

    {
        const float4* src = (const float4*)(qe_g + (size_t)b * 14 * 768);
        for (int i = tid; i < 14 * 768 / 4; i += 256) ((float4*)qe)[i] = src[i];
        const float* ws = wm_g + (size_t)b * 1400;
        for (int i = tid; i < 1400; i += 256) wm[i] = ws[i];
    }
    __syncthreads();

    float g4a = g4[tid], b4a = b4[tid], g4b = g4[tid + 256], b4b = b4[tid + 256],
          g4c = g4[tid + 512], b4c = b4[tid + 512];
    float wa = wia[tid], wb = wia[tid + 256], wc_ = wia[tid + 512];

    for (int g = 0; g < 10; ++g) {
        float t0[10], t1[10], t2[10];
#pragma unroll
        for (int i = 0; i < 10; ++i) { t0[i] = 0.f; t1[i] = 0.f; t2[i] = 0.f; }
#pragma unroll
        for (int t = 0; t < 14; ++t) {
            float q0 = qe[t * 768 + tid], q1 = qe[t * 768 + tid + 256], q2 = qe[t * 768 + tid + 512];
#pragma unroll
            for (int i = 0; i < 10; ++i) {
                float w = wm[t * 100 + g * 10 + i];
                t0[i] = fmaf(w, q0, t0[i]); t1[i] = fmaf(w, q1, t1[i]); t2[i] = fmaf(w, q2, t2[i]);
            }
        }
#pragma unroll
        for (int i = 0; i < 10; ++i) {
            const unsigned short* ie = imgCE + ((size_t)b * 100 + g * 10 + i) * 1536 + 768;
            t0[i] += bf2f(ie[tid]); t1[i] += bf2f(ie[tid + 256]); t2[i] += bf2f(ie[tid + 512]);
            float s = wave_sum(t0[i] + t1[i] + t2[i]);
            float q = wave_sum(t0[i] * t0[i] + t1[i] * t1[i] + t2[i] * t2[i]);
            if (lane == 0) { red[wid][i] = s; red[wid][10 + i] = q; }
        }
        __syncthreads();
        if (tid < 10) {
            float s = red[0][tid] + red[1][tid] + red[2][tid] + red[3][tid];
            float q = red[0][10 + tid] + red[1][10 + tid] + red[2][10 + tid] + red[3][10 + tid];
            float mu = s * (1.f / 768.f);
            float var = q * (1.f / 768.f) - mu * mu;
            mu_s[tid] = mu; rs_s[tid] = rsqrtf(var + 1e-3f);
        }
        __syncthreads();
#pragma unroll
        for (int i = 0; i < 10; ++i) {
            float mu = mu_s[i], rs = rs_s[i];
            float v0 = fmaxf((t0[i] - mu) * rs * g4a + b4a, 0.f);
            float v1 = fmaxf((t1[i] - mu) * rs * g4b + b4b, 0.f);
            float v2 = fmaxf((t2[i] - mu) * rs * g4c + b4c, 0.f);
            float p = wave_sum(v0 * wa + v1 * wb + v2 * wc_);
            if (lane == 0) red[wid][i] = p;
        }
        __syncthreads();
        if (tid < 10) ia_s[g * 10 + tid] = red[0][tid] + red[1][tid] + red[2][tid] + red[3][tid] + bia[0];
        __syncthreads();
    }

    if (wid == 0) {
        float x0 = ia_s[lane];
        float x1 = (lane + 64 < 100) ? ia_s[lane + 64] : 0.f;
        float s = wave_sum(x0 + x1);
        float q = wave_sum(x0 * x0 + x1 * x1);
        float mu = s * 0.01f;
        float var = q * 0.01f - mu * mu;
        float rs = rsqrtf(var + 1e-3f);
        float v0 = (x0 - mu) * rs * g5[lane] + b5[lane];
        float v1 = (lane + 64 < 100) ? (x1 - mu) * rs * g5[lane + 64] + b5[lane + 64] : -1e30f;
        float mx = wave_max(fmaxf(v0, v1));
        float e0 = expf(v0 - mx);
        float e1 = (lane + 64 < 100) ? expf(v1 - mx) : 0.f;
        float se = wave_sum(e0 + e1);
        float inv = 1.f / se;
        iw_s[lane] = e0 * inv;
        if (lane + 64 < 100) iw_s[lane + 64] = e1 * inv;
    }
    __syncthreads();

    const unsigned short* imf = imf_bf + (size_t)b * 100 * 2048;
    float acc8[8];
#pragma unroll
    for (int j = 0; j < 8; ++j) acc8[j] = 0.f;
    for (int n = 0; n < 100; ++n) {
        ushort8_t v = *(const ushort8_t*)(imf + (size_t)n * 2048 + tid * 8);
        float w = iw_s[n];
#pragma unroll
        for (int j = 0; j < 8; ++j) acc8[j] = fmaf(w, bf2f(v[j]), acc8[j]);
    }
    float4* dst = (float4*)(out_i + (size_t)b * 2048);
    float4 oA = {acc8[0], acc8[1], acc8[2], acc8[3]};
    float4 oB = {acc8[4], acc8[5], acc8[6], acc8[7]};
    dst[tid * 2] = oA; dst[tid * 2 + 1] = oB;
}

// ---------- launch ----------
extern "C" void kernel_launch(void* const* d_in, const int* in_sizes, int n_in,
                              void* d_out, int out_size, void* d_ws, size_t ws_size,
                              hipStream_t stream)
{
    const float* img_feat = (const float*)d_in[0];
    const float* ques_feat = (const float*)d_in[1];
    const float* Wc = (const float*)d_in[2];
    const float* bc = (const float*)d_in[3];
    const float* Wq = (const float*)d_in[4];
    const float* bq = (const float*)d_in[5];
    const float* Wi = (const float*)d_in[6];
    const float* bi = (const float*)d_in[7];
    const float* wqa = (const float*)d_in[8];
    const float* bqa = (const float*)d_in[9];
    const float* wia = (const float*)d_in[10];
    const float* bia = (const float*)d_in[11];
    const float* g1 = (const float*)d_in[12]; const float* b1 = (const float*)d_in[13];
    const float* g2 = (const float*)d_in[14]; const float* b2 = (const float*)d_in[15];
    const float* g3 = (const float*)d_in[16]; const float* b3 = (const float*)d_in[17];
    const float* g4 = (const float*)d_in[18]; const float* b4 = (const float*)d_in[19];
    const float* g5 = (const float*)d_in[20]; const float* b5 = (const float*)d_in[21];

    // workspace layout (bytes)
    const size_t SZ_WP   = 1536u * 2048u * 2u;
    const size_t SZ_WQT  = 768u * 768u * 2u;
    const size_t SZ_IMG  = 51200ull * 1536u * 2u;     // bf16
    const size_t SZ_QE   = 7168u * 768u * 4u;         // f32
    const size_t SZ_WM   = 512u * 1400u * 4u;
    const size_t SZ_ABF  = 51200ull * 2048u * 2u;
    const size_t SZ_QBF  = 7168u * 768u * 2u;

    const size_t OFF_WP  = 0;
    const size_t OFF_WQT = OFF_WP + SZ_WP;
    const size_t OFF_IMG = OFF_WQT + SZ_WQT;
    const size_t OFF_QE  = OFF_IMG + SZ_IMG;
    const size_t OFF_WM  = OFF_QE + SZ_QE;
    const size_t OFF_ABF = OFF_WM + SZ_WM;
    const size_t OFF_QBF = OFF_ABF + SZ_ABF;
    const size_t NEED    = OFF_QBF + SZ_QBF;
    if (ws_size < NEED) return;

    char* ws = (char*)d_ws;
    unsigned short* Wp    = (unsigned short*)(ws + OFF_WP);
    unsigned short* Wqt   = (unsigned short*)(ws + OFF_WQT);
    unsigned short* imgCE = (unsigned short*)(ws + OFF_IMG);
    float*          qe    = (float*)(ws + OFF_QE);
    float*          wm    = (float*)(ws + OFF_WM);
    unsigned short* Abf   = (unsigned short*)(ws + OFF_ABF);
    unsigned short* Qbf   = (unsigned short*)(ws + OFF_QBF);

    float* out_img = (float*)d_out;                   // [512][2048]
    float* out_q   = (float*)d_out + 512 * 2048;      // [512][768]

    hipLaunchKernelGGL(pack_w,  dim3(1536, 8), dim3(256), 0, stream, Wc, Wi, Wp);
    hipLaunchKernelGGL(pack_wq, dim3(768, 3),  dim3(256), 0, stream, Wq, Wqt);
    hipLaunchKernelGGL(cvt_bf16, dim3(2048), dim3(256), 0, stream,
                       img_feat, Abf, (long)(51200ull * 2048u / 8u));
    hipLaunchKernelGGL(cvt_bf16, dim3(1024), dim3(256), 0, stream,
                       ques_feat, Qbf, (long)(7168u * 768u / 8u));

    // imgCE(bf16) = img_feat @ [Wc|Wi] + [bc|bi]   (M=51200, N=1536, K=2048)
    hipLaunchKernelGGL(HIP_KERNEL_NAME(gemm8<1>), dim3(1200), dim3(512), 0, stream,
                       Abf, Wp, bc, bi, 768, (void*)imgCE, 1536, 2048, 6);
    // qe(f32) = ques_feat @ Wq + bq                (M=7168, N=768, K=768)
    hipLaunchKernelGGL(HIP_KERNEL_NAME(gemm8<0>), dim3(84), dim3(512), 0, stream,
                       Qbf, Wqt, bq, bq, 768, (void*)qe, 768, 768, 3);

    hipLaunchKernelGGL(wm_kernel, dim3(512), dim3(256), 0, stream,
                       Qbf, imgCE, g1, b1, wm);
    hipLaunchKernelGGL(ques_kernel, dim3(512), dim3(256), 0, stream,
                       ques_feat, qe, imgCE, wm, g2, b2, g3, b3, wqa, bqa, out_q);
    hipLaunchKernelGGL(img_kernel, dim3(512), dim3(256), 0, stream,
                       Abf, qe, imgCE, wm, g4, b4, g5, b5, wia, bia, out_img);
}

// Round 7
// 788.226 us; speedup vs baseline: 1.1466x; 1.0135x over previous
//
#include <hip/hip_runtime.h>

// ---------- types & helpers ----------
using f32x4     = __attribute__((ext_vector_type(4))) float;
using bf16x8    = __attribute__((ext_vector_type(8))) short;
using ushort8_t = __attribute__((ext_vector_type(8))) unsigned short;

__device__ __forceinline__ unsigned short f2bf(float f) {
    unsigned u = __builtin_bit_cast(unsigned, f);
    u += 0x7fffu + ((u >> 16) & 1u);   // RNE
    return (unsigned short)(u >> 16);
}
__device__ __forceinline__ float bf2f(unsigned short h) {
    return __builtin_bit_cast(float, (unsigned)h << 16);
}

__device__ __forceinline__ float wave_sum(float v) {
#pragma unroll
    for (int off = 32; off > 0; off >>= 1) v += __shfl_xor(v, off, 64);
    return v;
}
__device__ __forceinline__ float wave_max(float v) {
#pragma unroll
    for (int off = 32; off > 0; off >>= 1) v = fmaxf(v, __shfl_xor(v, off, 64));
    return v;
}

#define GLP(p)  ((const __attribute__((address_space(1))) void*)(p))
#define LDSP(p) ((__attribute__((address_space(3))) void*)(p))

// ---------- f32 -> bf16 bulk convert ----------
__global__ __launch_bounds__(256) void cvt_bf16(const float* __restrict__ in,
                                                unsigned short* __restrict__ out, long n8) {
    long i = (long)blockIdx.x * 256 + threadIdx.x;
    long stride = (long)gridDim.x * 256;
    for (; i < n8; i += stride) {
        const float4* p = (const float4*)(in + i * 8);
        float4 a = p[0], b = p[1];
        ushort8_t v;
        v[0] = f2bf(a.x); v[1] = f2bf(a.y); v[2] = f2bf(a.z); v[3] = f2bf(a.w);
        v[4] = f2bf(b.x); v[5] = f2bf(b.y); v[6] = f2bf(b.z); v[7] = f2bf(b.w);
        *(ushort8_t*)(out + i * 8) = v;
    }
}

// ---------- weight pack (transpose -> bf16, [N][K] row-major) ----------
__global__ void pack_w(const float* __restrict__ Wc, const float* __restrict__ Wi,
                       unsigned short* __restrict__ Wp) {
    int n = blockIdx.x, k = blockIdx.y * 256 + threadIdx.x;
    float v = (n < 768) ? Wc[(size_t)k * 768 + n] : Wi[(size_t)k * 768 + (n - 768)];
    Wp[(size_t)n * 2048 + k] = f2bf(v);
}

__global__ void pack_wq(const float* __restrict__ Wq, unsigned short* __restrict__ Wqt) {
    int n = blockIdx.x, k = blockIdx.y * 256 + threadIdx.x;
    Wqt[(size_t)n * 768 + k] = f2bf(Wq[(size_t)k * 768 + n]);
}

// ---------- 256x256 bf16 GEMM, 8-phase, vmcnt(6)/3-phase gate slack ----------
// C[M][N] = A[M][K] @ Bt[N][K]^T + bias.  BK=64, 2 K-tiles/iter.
// Stage plan (per iter i; t0=2i buf0, t1=2i+1 buf1):
//   ph1:A1(t1)  ph3:B0(t0+2)  ph4:B1(t0+2)+A0(t0+2)+gate(t1,vmcnt6)
//   ph5:A1(t0+2)  ph7:B0(t1+2)  ph8:B1(t1+2)+A0(t1+2)+gate(t0+2,vmcnt6)
// Ledger: A-plane[h] of a buf is read by wr==h waves at phases {1,3} (buf0) / {5,7} (buf1);
// B-plane[h] by wc>>1==h waves at {1,2}/{5,6}. Every stage issues after the post-MFMA
// barrier following the last reader's lgkmcnt(0) -> safe. Gates drain exactly the 6
// loads younger than the gated tile's last load. Never vmcnt(0) mid-loop.
template <int OUTBF>
__global__ __launch_bounds__(512, 1) void gemm8(
    const unsigned short* __restrict__ A, const unsigned short* __restrict__ Bt,
    const float* __restrict__ bias0, const float* __restrict__ bias1, int nsplit,
    void* __restrict__ Cv, int N, int K, int NTN)
{
    __shared__ unsigned short LA[2][2][8192];
    __shared__ unsigned short LB[2][2][8192];
    const int tid = threadIdx.x, lane = tid & 63, wid = tid >> 6;

    int nwg = (int)gridDim.x, bid = (int)blockIdx.x;
    if ((nwg & 7) == 0) { int cpx = nwg >> 3; bid = (bid & 7) * cpx + (bid >> 3); }  // T1
    const int tn = bid % NTN, tm = bid / NTN;
    const size_t m0 = (size_t)tm * 256, n0 = (size_t)tn * 256;
    const int NT = K >> 6;
    const int NIT = NT >> 1;

    const int wr = wid >> 2, wc = wid & 3;
    const int hb = wc >> 1;
    const int fr = lane & 15, fs = lane >> 4;

    const int r0 = tid >> 3, s0 = ((tid & 7) - r0) & 7;
    const int r1 = r0 + 64,  s1 = ((tid & 7) - r1) & 7;
    const unsigned short* pA[2][2];
    const unsigned short* pB[2][2];
#pragma unroll
    for (int h = 0; h < 2; ++h) {
        pA[h][0] = A  + (m0 + h * 128 + r0) * K + s0 * 8;
        pA[h][1] = A  + (m0 + h * 128 + r1) * K + s1 * 8;
        pB[h][0] = Bt + (n0 + h * 128 + r0) * K + s0 * 8;
        pB[h][1] = Bt + (n0 + h * 128 + r1) * K + s1 * 8;
    }
    const int d0 = tid * 8, d1 = (tid + 512) * 8;

#define STG_A(h, t, B_) do { \
    __builtin_amdgcn_global_load_lds(GLP(pA[h][0] + (size_t)(t) * 64), LDSP(&LA[B_][h][d0]), 16, 0, 0); \
    __builtin_amdgcn_global_load_lds(GLP(pA[h][1] + (size_t)(t) * 64), LDSP(&LA[B_][h][d1]), 16, 0, 0); \
} while (0)
#define STG_B(h, t, B_) do { \
    __builtin_amdgcn_global_load_lds(GLP(pB[h][0] + (size_t)(t) * 64), LDSP(&LB[B_][h][d0]), 16, 0, 0); \
    __builtin_amdgcn_global_load_lds(GLP(pB[h][1] + (size_t)(t) * 64), LDSP(&LB[B_][h][d1]), 16, 0, 0); \
} while (0)

    int offA[2][4], offB[2][2];
#pragma unroll
    for (int mq = 0; mq < 2; ++mq)
#pragma unroll
        for (int mfl = 0; mfl < 4; ++mfl) {
            int r = mq * 64 + mfl * 16 + fr;
            offA[mq][mfl] = r * 64 + ((fs + r) & 7) * 8;
        }
#pragma unroll
    for (int nq = 0; nq < 2; ++nq)
#pragma unroll
        for (int nfl = 0; nfl < 2; ++nfl) {
            int r = (wc & 1) * 64 + nq * 32 + nfl * 16 + fr;
            offB[nq][nfl] = r * 64 + ((fs + r) & 7) * 8;
        }

#define LDA_SUB(B_, mq) do { \
    _Pragma("unroll") \
    for (int mfl = 0; mfl < 4; ++mfl) { \
        av[mfl][0] = *(const bf16x8*)&LA[B_][wr][offA[mq][mfl]]; \
        av[mfl][1] = *(const bf16x8*)&LA[B_][wr][offA[mq][mfl] ^ 32]; \
    } } while (0)
#define LDB_SUB(B_, nq, bv) do { \
    _Pragma("unroll") \
    for (int nfl = 0; nfl < 2; ++nfl) { \
        bv[nfl][0] = *(const bf16x8*)&LB[B_][hb][offB[nq][nfl]]; \
        bv[nfl][1] = *(const bf16x8*)&LB[B_][hb][offB[nq][nfl] ^ 32]; \
    } } while (0)
#define MMA_Q(mq, nq, bv) do { \
    _Pragma("unroll") \
    for (int ks = 0; ks < 2; ++ks) \
    _Pragma("unroll") \
    for (int mfl = 0; mfl < 4; ++mfl) \
    _Pragma("unroll") \
    for (int nfl = 0; nfl < 2; ++nfl) \
        acc[mq * 4 + mfl][nq * 2 + nfl] = __builtin_amdgcn_mfma_f32_16x16x32_bf16( \
            av[mfl][ks], bv[nfl][ks], acc[mq * 4 + mfl][nq * 2 + nfl], 0, 0, 0); \
    } while (0)
#define BAR  __builtin_amdgcn_s_barrier()
#define SCB  __builtin_amdgcn_sched_barrier(0)
#define LGKM0 do { asm volatile("s_waitcnt lgkmcnt(0)" ::: "memory"); SCB; } while (0)
#define PRIO1 __builtin_amdgcn_s_setprio(1)
#define PRIO0 __builtin_amdgcn_s_setprio(0)

    f32x4 acc[8][4];
#pragma unroll
    for (int i = 0; i < 8; ++i)
#pragma unroll
        for (int j = 0; j < 4; ++j) acc[i][j] = (f32x4){0.f, 0.f, 0.f, 0.f};

    // prologue: tile0 full, tile1 B halves + A0 -> 14 loads, drain to 6 outstanding
    STG_A(0, 0, 0); STG_A(1, 0, 0); STG_B(0, 0, 0); STG_B(1, 0, 0);
    STG_B(0, 1, 1); STG_B(1, 1, 1); STG_A(0, 1, 1);
    asm volatile("s_waitcnt vmcnt(6)" ::: "memory");
    SCB; BAR;

    for (int i = 0; i < NIT; ++i) {
        const int t0 = 2 * i, t1 = 2 * i + 1;
        const bool st = (i + 1 < NIT);
        bf16x8 av[4][2], bv0[2][2], bv1[2][2];

        // ---- ph1 (t0: mq0,nq0) ----
        LDA_SUB(0, 0); LDB_SUB(0, 0, bv0);
        STG_A(1, t1, 1);
        BAR; LGKM0;
        PRIO1; MMA_Q(0, 0, bv0); PRIO0;
        BAR;
        // ---- ph2 (t0: mq0,nq1) ----
        LDB_SUB(0, 1, bv1);
        BAR; LGKM0;
        PRIO1; MMA_Q(0, 1, bv1); PRIO0;
        BAR;
        // ---- ph3 (t0: mq1,nq1) ----
        LDA_SUB(0, 1);
        if (st) STG_B(0, t0 + 2, 0);
        BAR; LGKM0;
        PRIO1; MMA_Q(1, 1, bv1); PRIO0;
        BAR;
        // ---- ph4 (t0: mq1,nq0) + gate t1 ----
        if (st) { STG_B(1, t0 + 2, 0); STG_A(0, t0 + 2, 0); }
        BAR;
        PRIO1; MMA_Q(1, 0, bv0); PRIO0;
        if (st) asm volatile("s_waitcnt vmcnt(6)" ::: "memory");
        else    asm volatile("s_waitcnt vmcnt(0)" ::: "memory");
        SCB; BAR;
        // ---- ph5 (t1: mq0,nq0) ----
        LDA_SUB(1, 0); LDB_SUB(1, 0, bv0);
        if (st) STG_A(1, t0 + 2, 0);
        BAR; LGKM0;
        PRIO1; MMA_Q(0, 0, bv0); PRIO0;
        BAR;
        // ---- ph6 (t1: mq0,nq1) ----
        LDB_SUB(1, 1, bv1);
        BAR; LGKM0;
        PRIO1; MMA_Q(0, 1, bv1); PRIO0;
        BAR;
        // ---- ph7 (t1: mq1,nq1) ----
        LDA_SUB(1, 1);
        if (st) STG_B(0, t1 + 2, 1);
        BAR; LGKM0;
        PRIO1; MMA_Q(1, 1, bv1); PRIO0;
        BAR;
        // ---- ph8 (t1: mq1,nq0) + gate next t0 ----
        if (st) { STG_B(1, t1 + 2, 1); STG_A(0, t1 + 2, 1); }
        BAR;
        PRIO1; MMA_Q(1, 0, bv0); PRIO0;
        if (st) asm volatile("s_waitcnt vmcnt(6)" ::: "memory");
        else    asm volatile("s_waitcnt vmcnt(0)" ::: "memory");
        SCB; BAR;
    }

#undef STG_A
#undef STG_B
#undef LDA_SUB
#undef LDB_SUB
#undef MMA_Q
#undef BAR
#undef SCB
#undef LGKM0
#undef PRIO1
#undef PRIO0

    // epilogue  (C/D layout: col = lane&15, row = (lane>>4)*4 + r)
    const int wm = wr * 128, wn = wc * 64;
#pragma unroll
    for (int nf = 0; nf < 4; ++nf) {
        int col = (int)n0 + wn + nf * 16 + fr;
        float bs = (col < nsplit) ? bias0[col] : bias1[col - nsplit];
#pragma unroll
        for (int mf = 0; mf < 8; ++mf) {
            size_t rowb = m0 + wm + mf * 16 + fs * 4;
#pragma unroll
            for (int r = 0; r < 4; ++r) {
                float v = acc[mf][nf][r] + bs;
                if (OUTBF) ((unsigned short*)Cv)[(rowb + r) * N + col] = f2bf(v);
                else       ((float*)Cv)[(rowb + r) * N + col] = v;
            }
        }
    }
}

// ---------- fused per-b kernel: wm (LDS-only) -> ques path -> img path ----------
__global__ __launch_bounds__(256) void fused_kernel(
    const float* __restrict__ qf_g, const unsigned short* __restrict__ qbf,
    const float* __restrict__ qe_g, const unsigned short* __restrict__ imgCE,
    const unsigned short* __restrict__ imf_bf,
    const float* __restrict__ g1, const float* __restrict__ b1,
    const float* __restrict__ g2, const float* __restrict__ b2,
    const float* __restrict__ g3, const float* __restrict__ b3,
    const float* __restrict__ g4, const float* __restrict__ b4,
    const float* __restrict__ g5, const float* __restrict__ b5,
    const float* __restrict__ wqa, const float* __restrict__ bqa,
    const float* __restrict__ wia, const float* __restrict__ bia,
    float* __restrict__ out_i, float* __restrict__ out_q)
{
    const int b = blockIdx.x, tid = threadIdx.x, lane = tid & 63, wid = tid >> 6;
    __shared__ float buf[14 * 768];        // qf (phase 1) then qe (phases 2-3), union
    __shared__ float wms[14 * 100];        // raw dots -> relu(LN) in place
    __shared__ float red[4][28];
    __shared__ float mu_s[14], rs_s[14], qa_s[14], qw_s[14];
    __shared__ float mu2_s[10], rs2_s[10];
    __shared__ float ia_s[100], iw_s[100];

    // ===== phase 1: wm =====
    {
        const ushort8_t* src = (const ushort8_t*)(qbf + (size_t)b * 14 * 768);
        for (int i = tid; i < 14 * 768 / 8; i += 256) {
            ushort8_t v = src[i];
#pragma unroll
            for (int j = 0; j < 8; ++j) buf[i * 8 + j] = bf2f(v[j]);
        }
    }
    __syncthreads();
    for (int n = wid; n < 100; n += 4) {
        const unsigned short* row = imgCE + ((size_t)b * 100 + n) * 1536;  // img_corr half
        float r[12];
#pragma unroll
        for (int j = 0; j < 12; ++j) r[j] = bf2f(row[lane + 64 * j]);
        for (int t = 0; t < 14; ++t) {
            const float* q = buf + t * 768;
            float s = 0.f;
#pragma unroll
            for (int j = 0; j < 12; ++j) s = fmaf(r[j], q[lane + 64 * j], s);
            s = wave_sum(s);
            if (lane == 0) wms[t * 100 + n] = s;
        }
    }
    __syncthreads();
    // LN_n + relu in place (row t owned by wave t%4)
    for (int t = wid; t < 14; t += 4) {
        float x0 = wms[t * 100 + lane];
        float x1 = (lane + 64 < 100) ? wms[t * 100 + lane + 64] : 0.f;
        float s = wave_sum(x0 + x1);
        float q = wave_sum(x0 * x0 + x1 * x1);
        float mu = s * (1.f / 100.f);
        float var = q * (1.f / 100.f) - mu * mu;
        float rs = rsqrtf(var + 1e-3f);
        {
            float v = (x0 - mu) * rs * g1[lane] + b1[lane];
            wms[t * 100 + lane] = v > 0.f ? v : 0.f;
        }
        if (lane + 64 < 100) {
            float v = (x1 - mu) * rs * g1[lane + 64] + b1[lane + 64];
            wms[t * 100 + lane + 64] = v > 0.f ? v : 0.f;
        }
    }
    // restage buf with qe (f32) — qf region no longer read
    {
        const float4* src = (const float4*)(qe_g + (size_t)b * 14 * 768);
        for (int i = tid; i < 14 * 768 / 4; i += 256) ((float4*)buf)[i] = src[i];
    }
    __syncthreads();

    // ===== phase 2: ques path =====
    {
        float a0[14], a1[14], a2[14];
#pragma unroll
        for (int t = 0; t < 14; ++t) { a0[t] = 0.f; a1[t] = 0.f; a2[t] = 0.f; }

        const unsigned short* ie_base = imgCE + (size_t)b * 100 * 1536 + 768;  // img_embed
        for (int n = 0; n < 100; ++n) {
            const unsigned short* ie = ie_base + (size_t)n * 1536;
            float e0 = bf2f(ie[tid]), e1 = bf2f(ie[tid + 256]), e2 = bf2f(ie[tid + 512]);
#pragma unroll
            for (int t = 0; t < 14; ++t) {
                float w = wms[t * 100 + n];
                a0[t] = fmaf(w, e0, a0[t]); a1[t] = fmaf(w, e1, a1[t]); a2[t] = fmaf(w, e2, a2[t]);
            }
        }
#pragma unroll
        for (int t = 0; t < 14; ++t) {
            a0[t] += buf[t * 768 + tid];
            a1[t] += buf[t * 768 + tid + 256];
            a2[t] += buf[t * 768 + tid + 512];
        }
#pragma unroll
        for (int t = 0; t < 14; ++t) {
            float s = wave_sum(a0[t] + a1[t] + a2[t]);
            float q = wave_sum(a0[t] * a0[t] + a1[t] * a1[t] + a2[t] * a2[t]);
            if (lane == 0) { red[wid][t] = s; red[wid][14 + t] = q; }
        }
        __syncthreads();
        if (tid < 14) {
            float s = red[0][tid] + red[1][tid] + red[2][tid] + red[3][tid];
            float q = red[0][14 + tid] + red[1][14 + tid] + red[2][14 + tid] + red[3][14 + tid];
            float mu = s * (1.f / 768.f);
            float var = q * (1.f / 768.f) - mu * mu;
            mu_s[tid] = mu; rs_s[tid] = rsqrtf(var + 1e-3f);
        }
        __syncthreads();

        float ga = g2[tid], ba = b2[tid], gb = g2[tid + 256], bb = b2[tid + 256],
              gc = g2[tid + 512], bc_ = b2[tid + 512];
        float w0 = wqa[tid], w1 = wqa[tid + 256], w2 = wqa[tid + 512];
#pragma unroll
        for (int t = 0; t < 14; ++t) {
            float mu = mu_s[t], rs = rs_s[t];
            float v0 = fmaxf((a0[t] - mu) * rs * ga + ba, 0.f);
            float v1 = fmaxf((a1[t] - mu) * rs * gb + bb, 0.f);
            float v2 = fmaxf((a2[t] - mu) * rs * gc + bc_, 0.f);
            float p = wave_sum(v0 * w0 + v1 * w1 + v2 * w2);
            if (lane == 0) red[wid][t] = p;
        }
        __syncthreads();
        if (tid < 14) qa_s[tid] = red[0][tid] + red[1][tid] + red[2][tid] + red[3][tid] + bqa[0];
        __syncthreads();
        if (tid == 0) {
            float s = 0.f;
            for (int t = 0; t < 14; ++t) s += qa_s[t];
            float mu = s * (1.f / 14.f);
            float q = 0.f;
            for (int t = 0; t < 14; ++t) { float d = qa_s[t] - mu; q += d * d; }
            float rs = rsqrtf(q * (1.f / 14.f) + 1e-3f);
            float e[14], mx = -1e30f;
            for (int t = 0; t < 14; ++t) { e[t] = (qa_s[t] - mu) * rs * g3[t] + b3[t]; mx = fmaxf(mx, e[t]); }
            float se = 0.f;
            for (int t = 0; t < 14; ++t) { e[t] = expf(e[t] - mx); se += e[t]; }
            float inv = 1.f / se;
            for (int t = 0; t < 14; ++t) qw_s[t] = e[t] * inv;
        }
        __syncthreads();

        const float* qf = qf_g + (size_t)b * 14 * 768;
#pragma unroll
        for (int c = 0; c < 3; ++c) {
            int h = tid + c * 256;
            float o = 0.f;
#pragma unroll
            for (int t = 0; t < 14; ++t) o = fmaf(qw_s[t], qf[t * 768 + h], o);
            out_q[(size_t)b * 768 + h] = o;
        }
    }
    __syncthreads();

    // ===== phase 3: img path =====
    {
        float g4a = g4[tid], b4a = b4[tid], g4b = g4[tid + 256], b4b = b4[tid + 256],
              g4c = g4[tid + 512], b4c = b4[tid + 512];
        float wa = wia[tid], wb = wia[tid + 256], wc_ = wia[tid + 512];

        for (int g = 0; g < 10; ++g) {
            float t0[10], t1[10], t2[10];
#pragma unroll
            for (int i = 0; i < 10; ++i) { t0[i] = 0.f; t1[i] = 0.f; t2[i] = 0.f; }
#pragma unroll
            for (int t = 0; t < 14; ++t) {
                float q0 = buf[t * 768 + tid], q1 = buf[t * 768 + tid + 256], q2 = buf[t * 768 + tid + 512];
#pragma unroll
                for (int i = 0; i < 10; ++i) {
                    float w = wms[t * 100 + g * 10 + i];
                    t0[i] = fmaf(w, q0, t0[i]); t1[i] = fmaf(w, q1, t1[i]); t2[i] = fmaf(w, q2, t2[i]);
                }
            }
#pragma unroll
            for (int i = 0; i < 10; ++i) {
                const unsigned short* ie = imgCE + ((size_t)b * 100 + g * 10 + i) * 1536 + 768;
                t0[i] += bf2f(ie[tid]); t1[i] += bf2f(ie[tid + 256]); t2[i] += bf2f(ie[tid + 512]);
                float s = wave_sum(t0[i] + t1[i] + t2[i]);
                float q = wave_sum(t0[i] * t0[i] + t1[i] * t1[i] + t2[i] * t2[i]);
                if (lane == 0) { red[wid][i] = s; red[wid][10 + i] = q; }
            }
            __syncthreads();
            if (tid < 10) {
                float s = red[0][tid] + red[1][tid] + red[2][tid] + red[3][tid];
                float q = red[0][10 + tid] + red[1][10 + tid] + red[2][10 + tid] + red[3][10 + tid];
                float mu = s * (1.f / 768.f);
                float var = q * (1.f / 768.f) - mu * mu;
                mu2_s[tid] = mu; rs2_s[tid] = rsqrtf(var + 1e-3f);
            }
            __syncthreads();
#pragma unroll
            for (int i = 0; i < 10; ++i) {
                float mu = mu2_s[i], rs = rs2_s[i];
                float v0 = fmaxf((t0[i] - mu) * rs * g4a + b4a, 0.f);
                float v1 = fmaxf((t1[i] - mu) * rs * g4b + b4b, 0.f);
                float v2 = fmaxf((t2[i] - mu) * rs * g4c + b4c, 0.f);
                float p = wave_sum(v0 * wa + v1 * wb + v2 * wc_);
                if (lane == 0) red[wid][i] = p;
            }
            __syncthreads();
            if (tid < 10) ia_s[g * 10 + tid] = red[0][tid] + red[1][tid] + red[2][tid] + red[3][tid] + bia[0];
            __syncthreads();
        }

        if (wid == 0) {
            float x0 = ia_s[lane];
            float x1 = (lane + 64 < 100) ? ia_s[lane + 64] : 0.f;
            float s = wave_sum(x0 + x1);
            float q = wave_sum(x0 * x0 + x1 * x1);
            float mu = s * 0.01f;
            float var = q * 0.01f - mu * mu;
            float rs = rsqrtf(var + 1e-3f);
            float v0 = (x0 - mu) * rs * g5[lane] + b5[lane];
            float v1 = (lane + 64 < 100) ? (x1 - mu) * rs * g5[lane + 64] + b5[lane + 64] : -1e30f;
            float mx = wave_max(fmaxf(v0, v1));
            float e0 = expf(v0 - mx);
            float e1 = (lane + 64 < 100) ? expf(v1 - mx) : 0.f;
            float se = wave_sum(e0 + e1);
            float inv = 1.f / se;
            iw_s[lane] = e0 * inv;
            if (lane + 64 < 100) iw_s[lane + 64] = e1 * inv;
        }
        __syncthreads();

        const unsigned short* imf = imf_bf + (size_t)b * 100 * 2048;
        float acc8[8];
#pragma unroll
        for (int j = 0; j < 8; ++j) acc8[j] = 0.f;
        for (int n = 0; n < 100; ++n) {
            ushort8_t v = *(const ushort8_t*)(imf + (size_t)n * 2048 + tid * 8);
            float w = iw_s[n];
#pragma unroll
            for (int j = 0; j < 8; ++j) acc8[j] = fmaf(w, bf2f(v[j]), acc8[j]);
        }
        float4* dst = (float4*)(out_i + (size_t)b * 2048);
        float4 oA = {acc8[0], acc8[1], acc8[2], acc8[3]};
        float4 oB = {acc8[4], acc8[5], acc8[6], acc8[7]};
        dst[tid * 2] = oA; dst[tid * 2 + 1] = oB;
    }
}

// ---------- launch ----------
extern "C" void kernel_launch(void* const* d_in, const int* in_sizes, int n_in,
                              void* d_out, int out_size, void* d_ws, size_t ws_size,
                              hipStream_t stream)
{
    const float* img_feat = (const float*)d_in[0];
    const float* ques_feat = (const float*)d_in[1];
    const float* Wc = (const float*)d_in[2];
    const float* bc = (const float*)d_in[3];
    const float* Wq = (const float*)d_in[4];
    const float* bq = (const float*)d_in[5];
    const float* Wi = (const float*)d_in[6];
    const float* bi = (const float*)d_in[7];
    const float* wqa = (const float*)d_in[8];
    const float* bqa = (const float*)d_in[9];
    const float* wia = (const float*)d_in[10];
    const float* bia = (const float*)d_in[11];
    const float* g1 = (const float*)d_in[12]; const float* b1 = (const float*)d_in[13];
    const float* g2 = (const float*)d_in[14]; const float* b2 = (const float*)d_in[15];
    const float* g3 = (const float*)d_in[16]; const float* b3 = (const float*)d_in[17];
    const float* g4 = (const float*)d_in[18]; const float* b4 = (const float*)d_in[19];
    const float* g5 = (const float*)d_in[20]; const float* b5 = (const float*)d_in[21];

    // workspace layout (bytes)
    const size_t SZ_WP   = 1536u * 2048u * 2u;
    const size_t SZ_WQT  = 768u * 768u * 2u;
    const size_t SZ_IMG  = 51200ull * 1536u * 2u;     // bf16
    const size_t SZ_QE   = 7168u * 768u * 4u;         // f32
    const size_t SZ_WM   = 512u * 1400u * 4u;         // (unused now)
    const size_t SZ_ABF  = 51200ull * 2048u * 2u;
    const size_t SZ_QBF  = 7168u * 768u * 2u;

    const size_t OFF_WP  = 0;
    const size_t OFF_WQT = OFF_WP + SZ_WP;
    const size_t OFF_IMG = OFF_WQT + SZ_WQT;
    const size_t OFF_QE  = OFF_IMG + SZ_IMG;
    const size_t OFF_WM  = OFF_QE + SZ_QE;
    const size_t OFF_ABF = OFF_WM + SZ_WM;
    const size_t OFF_QBF = OFF_ABF + SZ_ABF;
    const size_t NEED    = OFF_QBF + SZ_QBF;
    if (ws_size < NEED) return;

    char* ws = (char*)d_ws;
    unsigned short* Wp    = (unsigned short*)(ws + OFF_WP);
    unsigned short* Wqt   = (unsigned short*)(ws + OFF_WQT);
    unsigned short* imgCE = (unsigned short*)(ws + OFF_IMG);
    float*          qe    = (float*)(ws + OFF_QE);
    unsigned short* Abf   = (unsigned short*)(ws + OFF_ABF);
    unsigned short* Qbf   = (unsigned short*)(ws + OFF_QBF);

    float* out_img = (float*)d_out;                   // [512][2048]
    float* out_q   = (float*)d_out + 512 * 2048;      // [512][768]

    hipLaunchKernelGGL(pack_w,  dim3(1536, 8), dim3(256), 0, stream, Wc, Wi, Wp);
    hipLaunchKernelGGL(pack_wq, dim3(768, 3),  dim3(256), 0, stream, Wq, Wqt);
    hipLaunchKernelGGL(cvt_bf16, dim3(2048), dim3(256), 0, stream,
                       img_feat, Abf, (long)(51200ull * 2048u / 8u));
    hipLaunchKernelGGL(cvt_bf16, dim3(1024), dim3(256), 0, stream,
                       ques_feat, Qbf, (long)(7168u * 768u / 8u));

    // imgCE(bf16) = img_feat @ [Wc|Wi] + [bc|bi]   (M=51200, N=1536, K=2048)
    hipLaunchKernelGGL(HIP_KERNEL_NAME(gemm8<1>), dim3(1200), dim3(512), 0, stream,
                       Abf, Wp, bc, bi, 768, (void*)imgCE, 1536, 2048, 6);
    // qe(f32) = ques_feat @ Wq + bq                (M=7168, N=768, K=768)
    hipLaunchKernelGGL(HIP_KERNEL_NAME(gemm8<0>), dim3(84), dim3(512), 0, stream,
                       Qbf, Wqt, bq, bq, 768, (void*)qe, 768, 768, 3);

    hipLaunchKernelGGL(fused_kernel, dim3(512), dim3(256), 0, stream,
                       ques_feat, Qbf, qe, imgCE, Abf,
                       g1, b1, g2, b2, g3, b3, g4, b4, g5, b5,
                       wqa, bqa, wia, bia, out_img, out_q);
}

// Round 8
// 764.533 us; speedup vs baseline: 1.1821x; 1.0310x over previous
//
#include <hip/hip_runtime.h>

// ---------- types & helpers ----------
using f32x4     = __attribute__((ext_vector_type(4))) float;
using bf16x8    = __attribute__((ext_vector_type(8))) short;
using ushort8_t = __attribute__((ext_vector_type(8))) unsigned short;

__device__ __forceinline__ unsigned short f2bf(float f) {
    unsigned u = __builtin_bit_cast(unsigned, f);
    u += 0x7fffu + ((u >> 16) & 1u);   // RNE
    return (unsigned short)(u >> 16);
}
__device__ __forceinline__ float bf2f(unsigned short h) {
    return __builtin_bit_cast(float, (unsigned)h << 16);
}

__device__ __forceinline__ float wave_sum(float v) {
#pragma unroll
    for (int off = 32; off > 0; off >>= 1) v += __shfl_xor(v, off, 64);
    return v;
}
__device__ __forceinline__ float wave_max(float v) {
#pragma unroll
    for (int off = 32; off > 0; off >>= 1) v = fmaxf(v, __shfl_xor(v, off, 64));
    return v;
}

#define GLP(p)  ((const __attribute__((address_space(1))) void*)(p))
#define LDSP(p) ((__attribute__((address_space(3))) void*)(p))

// ---------- f32 -> bf16 bulk convert ----------
__global__ __launch_bounds__(256) void cvt_bf16(const float* __restrict__ in,
                                                unsigned short* __restrict__ out, long n8) {
    long i = (long)blockIdx.x * 256 + threadIdx.x;
    long stride = (long)gridDim.x * 256;
    for (; i < n8; i += stride) {
        const float4* p = (const float4*)(in + i * 8);
        float4 a = p[0], b = p[1];
        ushort8_t v;
        v[0] = f2bf(a.x); v[1] = f2bf(a.y); v[2] = f2bf(a.z); v[3] = f2bf(a.w);
        v[4] = f2bf(b.x); v[5] = f2bf(b.y); v[6] = f2bf(b.z); v[7] = f2bf(b.w);
        *(ushort8_t*)(out + i * 8) = v;
    }
}

// ---------- coalesced LDS-tiled weight transpose -> bf16 [N][K] ----------
// S row-major [K][nsplit]; D[n][K] = S(k, n mod nsplit), source S0 for n<nsplit else S1.
__global__ __launch_bounds__(256) void pack_t(
    const float* __restrict__ S0, const float* __restrict__ S1, int nsplit,
    unsigned short* __restrict__ D, int K)
{
    __shared__ float t[64][65];
    const int k0 = blockIdx.x * 64, n0 = blockIdx.y * 64;
    const float* S = (n0 < nsplit) ? S0 : S1;
    const int nb = (n0 < nsplit) ? n0 : n0 - nsplit;
    const int c = threadIdx.x & 63, r4 = threadIdx.x >> 6;
#pragma unroll
    for (int it = 0; it < 16; ++it) {
        int r = it * 4 + r4;
        t[r][c] = S[(size_t)(k0 + r) * nsplit + nb + c];   // coalesced 256B/wave
    }
    __syncthreads();
#pragma unroll
    for (int it = 0; it < 16; ++it) {
        int rn = it * 4 + r4;
        D[(size_t)(n0 + rn) * K + k0 + c] = f2bf(t[c][rn]); // coalesced write, pad kills conflicts
    }
}

// ---------- 256x256 bf16 GEMM, 8-phase (FROZEN from R7) ----------
template <int OUTBF>
__global__ __launch_bounds__(512, 1) void gemm8(
    const unsigned short* __restrict__ A, const unsigned short* __restrict__ Bt,
    const float* __restrict__ bias0, const float* __restrict__ bias1, int nsplit,
    void* __restrict__ Cv, int N, int K, int NTN)
{
    __shared__ unsigned short LA[2][2][8192];
    __shared__ unsigned short LB[2][2][8192];
    const int tid = threadIdx.x, lane = tid & 63, wid = tid >> 6;

    int nwg = (int)gridDim.x, bid = (int)blockIdx.x;
    if ((nwg & 7) == 0) { int cpx = nwg >> 3; bid = (bid & 7) * cpx + (bid >> 3); }  // T1
    const int tn = bid % NTN, tm = bid / NTN;
    const size_t m0 = (size_t)tm * 256, n0 = (size_t)tn * 256;
    const int NT = K >> 6;
    const int NIT = NT >> 1;

    const int wr = wid >> 2, wc = wid & 3;
    const int hb = wc >> 1;
    const int fr = lane & 15, fs = lane >> 4;

    const int r0 = tid >> 3, s0 = ((tid & 7) - r0) & 7;
    const int r1 = r0 + 64,  s1 = ((tid & 7) - r1) & 7;
    const unsigned short* pA[2][2];
    const unsigned short* pB[2][2];
#pragma unroll
    for (int h = 0; h < 2; ++h) {
        pA[h][0] = A  + (m0 + h * 128 + r0) * K + s0 * 8;
        pA[h][1] = A  + (m0 + h * 128 + r1) * K + s1 * 8;
        pB[h][0] = Bt + (n0 + h * 128 + r0) * K + s0 * 8;
        pB[h][1] = Bt + (n0 + h * 128 + r1) * K + s1 * 8;
    }
    const int d0 = tid * 8, d1 = (tid + 512) * 8;

#define STG_A(h, t, B_) do { \
    __builtin_amdgcn_global_load_lds(GLP(pA[h][0] + (size_t)(t) * 64), LDSP(&LA[B_][h][d0]), 16, 0, 0); \
    __builtin_amdgcn_global_load_lds(GLP(pA[h][1] + (size_t)(t) * 64), LDSP(&LA[B_][h][d1]), 16, 0, 0); \
} while (0)
#define STG_B(h, t, B_) do { \
    __builtin_amdgcn_global_load_lds(GLP(pB[h][0] + (size_t)(t) * 64), LDSP(&LB[B_][h][d0]), 16, 0, 0); \
    __builtin_amdgcn_global_load_lds(GLP(pB[h][1] + (size_t)(t) * 64), LDSP(&LB[B_][h][d1]), 16, 0, 0); \
} while (0)

    int offA[2][4], offB[2][2];
#pragma unroll
    for (int mq = 0; mq < 2; ++mq)
#pragma unroll
        for (int mfl = 0; mfl < 4; ++mfl) {
            int r = mq * 64 + mfl * 16 + fr;
            offA[mq][mfl] = r * 64 + ((fs + r) & 7) * 8;
        }
#pragma unroll
    for (int nq = 0; nq < 2; ++nq)
#pragma unroll
        for (int nfl = 0; nfl < 2; ++nfl) {
            int r = (wc & 1) * 64 + nq * 32 + nfl * 16 + fr;
            offB[nq][nfl] = r * 64 + ((fs + r) & 7) * 8;
        }

#define LDA_SUB(B_, mq) do { \
    _Pragma("unroll") \
    for (int mfl = 0; mfl < 4; ++mfl) { \
        av[mfl][0] = *(const bf16x8*)&LA[B_][wr][offA[mq][mfl]]; \
        av[mfl][1] = *(const bf16x8*)&LA[B_][wr][offA[mq][mfl] ^ 32]; \
    } } while (0)
#define LDB_SUB(B_, nq, bv) do { \
    _Pragma("unroll") \
    for (int nfl = 0; nfl < 2; ++nfl) { \
        bv[nfl][0] = *(const bf16x8*)&LB[B_][hb][offB[nq][nfl]]; \
        bv[nfl][1] = *(const bf16x8*)&LB[B_][hb][offB[nq][nfl] ^ 32]; \
    } } while (0)
#define MMA_Q(mq, nq, bv) do { \
    _Pragma("unroll") \
    for (int ks = 0; ks < 2; ++ks) \
    _Pragma("unroll") \
    for (int mfl = 0; mfl < 4; ++mfl) \
    _Pragma("unroll") \
    for (int nfl = 0; nfl < 2; ++nfl) \
        acc[mq * 4 + mfl][nq * 2 + nfl] = __builtin_amdgcn_mfma_f32_16x16x32_bf16( \
            av[mfl][ks], bv[nfl][ks], acc[mq * 4 + mfl][nq * 2 + nfl], 0, 0, 0); \
    } while (0)
#define BAR  __builtin_amdgcn_s_barrier()
#define SCB  __builtin_amdgcn_sched_barrier(0)
#define LGKM0 do { asm volatile("s_waitcnt lgkmcnt(0)" ::: "memory"); SCB; } while (0)
#define PRIO1 __builtin_amdgcn_s_setprio(1)
#define PRIO0 __builtin_amdgcn_s_setprio(0)

    f32x4 acc[8][4];
#pragma unroll
    for (int i = 0; i < 8; ++i)
#pragma unroll
        for (int j = 0; j < 4; ++j) acc[i][j] = (f32x4){0.f, 0.f, 0.f, 0.f};

    STG_A(0, 0, 0); STG_A(1, 0, 0); STG_B(0, 0, 0); STG_B(1, 0, 0);
    STG_B(0, 1, 1); STG_B(1, 1, 1); STG_A(0, 1, 1);
    asm volatile("s_waitcnt vmcnt(6)" ::: "memory");
    SCB; BAR;

    for (int i = 0; i < NIT; ++i) {
        const int t0 = 2 * i, t1 = 2 * i + 1;
        const bool st = (i + 1 < NIT);
        bf16x8 av[4][2], bv0[2][2], bv1[2][2];

        LDA_SUB(0, 0); LDB_SUB(0, 0, bv0);
        STG_A(1, t1, 1);
        BAR; LGKM0;
        PRIO1; MMA_Q(0, 0, bv0); PRIO0;
        BAR;

        LDB_SUB(0, 1, bv1);
        BAR; LGKM0;
        PRIO1; MMA_Q(0, 1, bv1); PRIO0;
        BAR;

        LDA_SUB(0, 1);
        if (st) STG_B(0, t0 + 2, 0);
        BAR; LGKM0;
        PRIO1; MMA_Q(1, 1, bv1); PRIO0;
        BAR;

        if (st) { STG_B(1, t0 + 2, 0); STG_A(0, t0 + 2, 0); }
        BAR;
        PRIO1; MMA_Q(1, 0, bv0); PRIO0;
        if (st) asm volatile("s_waitcnt vmcnt(6)" ::: "memory");
        else    asm volatile("s_waitcnt vmcnt(0)" ::: "memory");
        SCB; BAR;

        LDA_SUB(1, 0); LDB_SUB(1, 0, bv0);
        if (st) STG_A(1, t0 + 2, 0);
        BAR; LGKM0;
        PRIO1; MMA_Q(0, 0, bv0); PRIO0;
        BAR;

        LDB_SUB(1, 1, bv1);
        BAR; LGKM0;
        PRIO1; MMA_Q(0, 1, bv1); PRIO0;
        BAR;

        LDA_SUB(1, 1);
        if (st) STG_B(0, t1 + 2, 1);
        BAR; LGKM0;
        PRIO1; MMA_Q(1, 1, bv1); PRIO0;
        BAR;

        if (st) { STG_B(1, t1 + 2, 1); STG_A(0, t1 + 2, 1); }
        BAR;
        PRIO1; MMA_Q(1, 0, bv0); PRIO0;
        if (st) asm volatile("s_waitcnt vmcnt(6)" ::: "memory");
        else    asm volatile("s_waitcnt vmcnt(0)" ::: "memory");
        SCB; BAR;
    }

#undef STG_A
#undef STG_B
#undef LDA_SUB
#undef LDB_SUB
#undef MMA_Q
#undef BAR
#undef SCB
#undef LGKM0
#undef PRIO1
#undef PRIO0

    const int wm = wr * 128, wn = wc * 64;
#pragma unroll
    for (int nf = 0; nf < 4; ++nf) {
        int col = (int)n0 + wn + nf * 16 + fr;
        float bs = (col < nsplit) ? bias0[col] : bias1[col - nsplit];
#pragma unroll
        for (int mf = 0; mf < 8; ++mf) {
            size_t rowb = m0 + wm + mf * 16 + fs * 4;
#pragma unroll
            for (int r = 0; r < 4; ++r) {
                float v = acc[mf][nf][r] + bs;
                if (OUTBF) ((unsigned short*)Cv)[(rowb + r) * N + col] = f2bf(v);
                else       ((float*)Cv)[(rowb + r) * N + col] = v;
            }
        }
    }
}

// ---------- fused per-b kernel: wm (LDS-only) -> ques path -> img path ----------
__global__ __launch_bounds__(256) void fused_kernel(
    const float* __restrict__ qf_g, const unsigned short* __restrict__ qbf,
    const unsigned short* __restrict__ qe_g, const unsigned short* __restrict__ imgCE,
    const unsigned short* __restrict__ imf_bf,
    const float* __restrict__ g1, const float* __restrict__ b1,
    const float* __restrict__ g2, const float* __restrict__ b2,
    const float* __restrict__ g3, const float* __restrict__ b3,
    const float* __restrict__ g4, const float* __restrict__ b4,
    const float* __restrict__ g5, const float* __restrict__ b5,
    const float* __restrict__ wqa, const float* __restrict__ bqa,
    const float* __restrict__ wia, const float* __restrict__ bia,
    float* __restrict__ out_i, float* __restrict__ out_q)
{
    const int b = blockIdx.x, tid = threadIdx.x, lane = tid & 63, wid = tid >> 6;
    __shared__ float buf[14 * 768];        // qf (phase 1) then qe (phases 2-3), union
    __shared__ float wms[14 * 100];
    __shared__ float red[4][28];
    __shared__ float mu_s[14], rs_s[14], qa_s[14], qw_s[14];
    __shared__ float mu2_s[10], rs2_s[10];
    __shared__ float ia_s[100], iw_s[100];

    // ===== phase 1: wm =====
    {
        const ushort8_t* src = (const ushort8_t*)(qbf + (size_t)b * 14 * 768);
        for (int i = tid; i < 14 * 768 / 8; i += 256) {
            ushort8_t v = src[i];
#pragma unroll
            for (int j = 0; j < 8; ++j) buf[i * 8 + j] = bf2f(v[j]);
        }
    }
    __syncthreads();
    for (int n = wid; n < 100; n += 4) {
        const unsigned short* row = imgCE + ((size_t)b * 100 + n) * 1536;  // img_corr half
        float r[12];
#pragma unroll
        for (int j = 0; j < 12; ++j) r[j] = bf2f(row[lane + 64 * j]);
        for (int t = 0; t < 14; ++t) {
            const float* q = buf + t * 768;
            float s = 0.f;
#pragma unroll
            for (int j = 0; j < 12; ++j) s = fmaf(r[j], q[lane + 64 * j], s);
            s = wave_sum(s);
            if (lane == 0) wms[t * 100 + n] = s;
        }
    }
    __syncthreads();
    for (int t = wid; t < 14; t += 4) {
        float x0 = wms[t * 100 + lane];
        float x1 = (lane + 64 < 100) ? wms[t * 100 + lane + 64] : 0.f;
        float s = wave_sum(x0 + x1);
        float q = wave_sum(x0 * x0 + x1 * x1);
        float mu = s * (1.f / 100.f);
        float var = q * (1.f / 100.f) - mu * mu;
        float rs = rsqrtf(var + 1e-3f);
        {
            float v = (x0 - mu) * rs * g1[lane] + b1[lane];
            wms[t * 100 + lane] = v > 0.f ? v : 0.f;
        }
        if (lane + 64 < 100) {
            float v = (x1 - mu) * rs * g1[lane + 64] + b1[lane + 64];
            wms[t * 100 + lane + 64] = v > 0.f ? v : 0.f;
        }
    }
    // restage buf with qe (bf16)
    {
        const ushort8_t* src = (const ushort8_t*)(qe_g + (size_t)b * 14 * 768);
        for (int i = tid; i < 14 * 768 / 8; i += 256) {
            ushort8_t v = src[i];
#pragma unroll
            for (int j = 0; j < 8; ++j) buf[i * 8 + j] = bf2f(v[j]);
        }
    }
    __syncthreads();

    // ===== phase 2: ques path =====
    {
        float a0[14], a1[14], a2[14];
#pragma unroll
        for (int t = 0; t < 14; ++t) { a0[t] = 0.f; a1[t] = 0.f; a2[t] = 0.f; }

        const unsigned short* ie_base = imgCE + (size_t)b * 100 * 1536 + 768;  // img_embed
        float e0n = bf2f(ie_base[tid]), e1n = bf2f(ie_base[tid + 256]), e2n = bf2f(ie_base[tid + 512]);
        for (int n = 0; n < 100; ++n) {
            float e0 = e0n, e1 = e1n, e2 = e2n;
            if (n < 99) {                         // prefetch next row (hide L2/L3 latency)
                const unsigned short* ie = ie_base + (size_t)(n + 1) * 1536;
                e0n = bf2f(ie[tid]); e1n = bf2f(ie[tid + 256]); e2n = bf2f(ie[tid + 512]);
            }
#pragma unroll
            for (int t = 0; t < 14; ++t) {
                float w = wms[t * 100 + n];
                a0[t] = fmaf(w, e0, a0[t]); a1[t] = fmaf(w, e1, a1[t]); a2[t] = fmaf(w, e2, a2[t]);
            }
        }
#pragma unroll
        for (int t = 0; t < 14; ++t) {
            a0[t] += buf[t * 768 + tid];
            a1[t] += buf[t * 768 + tid + 256];
            a2[t] += buf[t * 768 + tid + 512];
        }
#pragma unroll
        for (int t = 0; t < 14; ++t) {
            float s = wave_sum(a0[t] + a1[t] + a2[t]);
            float q = wave_sum(a0[t] * a0[t] + a1[t] * a1[t] + a2[t] * a2[t]);
            if (lane == 0) { red[wid][t] = s; red[wid][14 + t] = q; }
        }
        __syncthreads();
        if (tid < 14) {
            float s = red[0][tid] + red[1][tid] + red[2][tid] + red[3][tid];
            float q = red[0][14 + tid] + red[1][14 + tid] + red[2][14 + tid] + red[3][14 + tid];
            float mu = s * (1.f / 768.f);
            float var = q * (1.f / 768.f) - mu * mu;
            mu_s[tid] = mu; rs_s[tid] = rsqrtf(var + 1e-3f);
        }
        __syncthreads();

        float ga = g2[tid], ba = b2[tid], gb = g2[tid + 256], bb = b2[tid + 256],
              gc = g2[tid + 512], bc_ = b2[tid + 512];
        float w0 = wqa[tid], w1 = wqa[tid + 256], w2 = wqa[tid + 512];
#pragma unroll
        for (int t = 0; t < 14; ++t) {
            float mu = mu_s[t], rs = rs_s[t];
            float v0 = fmaxf((a0[t] - mu) * rs * ga + ba, 0.f);
            float v1 = fmaxf((a1[t] - mu) * rs * gb + bb, 0.f);
            float v2 = fmaxf((a2[t] - mu) * rs * gc + bc_, 0.f);
            float p = wave_sum(v0 * w0 + v1 * w1 + v2 * w2);
            if (lane == 0) red[wid][t] = p;
        }
        __syncthreads();
        if (tid < 14) qa_s[tid] = red[0][tid] + red[1][tid] + red[2][tid] + red[3][tid] + bqa[0];
        __syncthreads();
        if (tid == 0) {
            float s = 0.f;
            for (int t = 0; t < 14; ++t) s += qa_s[t];
            float mu = s * (1.f / 14.f);
            float q = 0.f;
            for (int t = 0; t < 14; ++t) { float d = qa_s[t] - mu; q += d * d; }
            float rs = rsqrtf(q * (1.f / 14.f) + 1e-3f);
            float e[14], mx = -1e30f;
            for (int t = 0; t < 14; ++t) { e[t] = (qa_s[t] - mu) * rs * g3[t] + b3[t]; mx = fmaxf(mx, e[t]); }
            float se = 0.f;
            for (int t = 0; t < 14; ++t) { e[t] = expf(e[t] - mx); se += e[t]; }
            float inv = 1.f / se;
            for (int t = 0; t < 14; ++t) qw_s[t] = e[t] * inv;
        }
        __syncthreads();

        const float* qf = qf_g + (size_t)b * 14 * 768;
#pragma unroll
        for (int c = 0; c < 3; ++c) {
            int h = tid + c * 256;
            float o = 0.f;
#pragma unroll
            for (int t = 0; t < 14; ++t) o = fmaf(qw_s[t], qf[t * 768 + h], o);
            out_q[(size_t)b * 768 + h] = o;
        }
    }
    __syncthreads();

    // ===== phase 3: img path =====
    {
        float g4a = g4[tid], b4a = b4[tid], g4b = g4[tid + 256], b4b = b4[tid + 256],
              g4c = g4[tid + 512], b4c = b4[tid + 512];
        float wa = wia[tid], wb = wia[tid + 256], wc_ = wia[tid + 512];

        for (int g = 0; g < 10; ++g) {
            // hoist this group's img_embed loads ahead of the FMA block
            float ge0[10], ge1[10], ge2[10];
#pragma unroll
            for (int i = 0; i < 10; ++i) {
                const unsigned short* ie = imgCE + ((size_t)b * 100 + g * 10 + i) * 1536 + 768;
                ge0[i] = bf2f(ie[tid]); ge1[i] = bf2f(ie[tid + 256]); ge2[i] = bf2f(ie[tid + 512]);
            }
            float t0[10], t1[10], t2[10];
#pragma unroll
            for (int i = 0; i < 10; ++i) { t0[i] = 0.f; t1[i] = 0.f; t2[i] = 0.f; }
#pragma unroll
            for (int t = 0; t < 14; ++t) {
                float q0 = buf[t * 768 + tid], q1 = buf[t * 768 + tid + 256], q2 = buf[t * 768 + tid + 512];
#pragma unroll
                for (int i = 0; i < 10; ++i) {
                    float w = wms[t * 100 + g * 10 + i];
                    t0[i] = fmaf(w, q0, t0[i]); t1[i] = fmaf(w, q1, t1[i]); t2[i] = fmaf(w, q2, t2[i]);
                }
            }
#pragma unroll
            for (int i = 0; i < 10; ++i) {
                t0[i] += ge0[i]; t1[i] += ge1[i]; t2[i] += ge2[i];
                float s = wave_sum(t0[i] + t1[i] + t2[i]);
                float q = wave_sum(t0[i] * t0[i] + t1[i] * t1[i] + t2[i] * t2[i]);
                if (lane == 0) { red[wid][i] = s; red[wid][10 + i] = q; }
            }
            __syncthreads();
            if (tid < 10) {
                float s = red[0][tid] + red[1][tid] + red[2][tid] + red[3][tid];
                float q = red[0][10 + tid] + red[1][10 + tid] + red[2][10 + tid] + red[3][10 + tid];
                float mu = s * (1.f / 768.f);
                float var = q * (1.f / 768.f) - mu * mu;
                mu2_s[tid] = mu; rs2_s[tid] = rsqrtf(var + 1e-3f);
            }
            __syncthreads();
#pragma unroll
            for (int i = 0; i < 10; ++i) {
                float mu = mu2_s[i], rs = rs2_s[i];
                float v0 = fmaxf((t0[i] - mu) * rs * g4a + b4a, 0.f);
                float v1 = fmaxf((t1[i] - mu) * rs * g4b + b4b, 0.f);
                float v2 = fmaxf((t2[i] - mu) * rs * g4c + b4c, 0.f);
                float p = wave_sum(v0 * wa + v1 * wb + v2 * wc_);
                if (lane == 0) red[wid][i] = p;
            }
            __syncthreads();
            if (tid < 10) ia_s[g * 10 + tid] = red[0][tid] + red[1][tid] + red[2][tid] + red[3][tid] + bia[0];
            __syncthreads();
        }

        if (wid == 0) {
            float x0 = ia_s[lane];
            float x1 = (lane + 64 < 100) ? ia_s[lane + 64] : 0.f;
            float s = wave_sum(x0 + x1);
            float q = wave_sum(x0 * x0 + x1 * x1);
            float mu = s * 0.01f;
            float var = q * 0.01f - mu * mu;
            float rs = rsqrtf(var + 1e-3f);
            float v0 = (x0 - mu) * rs * g5[lane] + b5[lane];
            float v1 = (lane + 64 < 100) ? (x1 - mu) * rs * g5[lane + 64] + b5[lane + 64] : -1e30f;
            float mx = wave_max(fmaxf(v0, v1));
            float e0 = expf(v0 - mx);
            float e1 = (lane + 64 < 100) ? expf(v1 - mx) : 0.f;
            float se = wave_sum(e0 + e1);
            float inv = 1.f / se;
            iw_s[lane] = e0 * inv;
            if (lane + 64 < 100) iw_s[lane + 64] = e1 * inv;
        }
        __syncthreads();

        const unsigned short* imf = imf_bf + (size_t)b * 100 * 2048;
        float acc8[8];
#pragma unroll
        for (int j = 0; j < 8; ++j) acc8[j] = 0.f;
        for (int n = 0; n < 100; ++n) {
            ushort8_t v = *(const ushort8_t*)(imf + (size_t)n * 2048 + tid * 8);
            float w = iw_s[n];
#pragma unroll
            for (int j = 0; j < 8; ++j) acc8[j] = fmaf(w, bf2f(v[j]), acc8[j]);
        }
        float4* dst = (float4*)(out_i + (size_t)b * 2048);
        float4 oA = {acc8[0], acc8[1], acc8[2], acc8[3]};
        float4 oB = {acc8[4], acc8[5], acc8[6], acc8[7]};
        dst[tid * 2] = oA; dst[tid * 2 + 1] = oB;
    }
}

// ---------- launch ----------
extern "C" void kernel_launch(void* const* d_in, const int* in_sizes, int n_in,
                              void* d_out, int out_size, void* d_ws, size_t ws_size,
                              hipStream_t stream)
{
    const float* img_feat = (const float*)d_in[0];
    const float* ques_feat = (const float*)d_in[1];
    const float* Wc = (const float*)d_in[2];
    const float* bc = (const float*)d_in[3];
    const float* Wq = (const float*)d_in[4];
    const float* bq = (const float*)d_in[5];
    const float* Wi = (const float*)d_in[6];
    const float* bi = (const float*)d_in[7];
    const float* wqa = (const float*)d_in[8];
    const float* bqa = (const float*)d_in[9];
    const float* wia = (const float*)d_in[10];
    const float* bia = (const float*)d_in[11];
    const float* g1 = (const float*)d_in[12]; const float* b1 = (const float*)d_in[13];
    const float* g2 = (const float*)d_in[14]; const float* b2 = (const float*)d_in[15];
    const float* g3 = (const float*)d_in[16]; const float* b3 = (const float*)d_in[17];
    const float* g4 = (const float*)d_in[18]; const float* b4 = (const float*)d_in[19];
    const float* g5 = (const float*)d_in[20]; const float* b5 = (const float*)d_in[21];

    // workspace layout (bytes)
    const size_t SZ_WP   = 1536u * 2048u * 2u;
    const size_t SZ_WQT  = 768u * 768u * 2u;
    const size_t SZ_IMG  = 51200ull * 1536u * 2u;     // bf16
    const size_t SZ_QE   = 7168u * 768u * 4u;         // reserve f32-size (bf16 used)
    const size_t SZ_WM   = 512u * 1400u * 4u;
    const size_t SZ_ABF  = 51200ull * 2048u * 2u;
    const size_t SZ_QBF  = 7168u * 768u * 2u;

    const size_t OFF_WP  = 0;
    const size_t OFF_WQT = OFF_WP + SZ_WP;
    const size_t OFF_IMG = OFF_WQT + SZ_WQT;
    const size_t OFF_QE  = OFF_IMG + SZ_IMG;
    const size_t OFF_WM  = OFF_QE + SZ_QE;
    const size_t OFF_ABF = OFF_WM + SZ_WM;
    const size_t OFF_QBF = OFF_ABF + SZ_ABF;
    const size_t NEED    = OFF_QBF + SZ_QBF;
    if (ws_size < NEED) return;

    char* ws = (char*)d_ws;
    unsigned short* Wp    = (unsigned short*)(ws + OFF_WP);
    unsigned short* Wqt   = (unsigned short*)(ws + OFF_WQT);
    unsigned short* imgCE = (unsigned short*)(ws + OFF_IMG);
    unsigned short* qe    = (unsigned short*)(ws + OFF_QE);
    unsigned short* Abf   = (unsigned short*)(ws + OFF_ABF);
    unsigned short* Qbf   = (unsigned short*)(ws + OFF_QBF);

    float* out_img = (float*)d_out;                   // [512][2048]
    float* out_q   = (float*)d_out + 512 * 2048;      // [512][768]

    hipLaunchKernelGGL(pack_t, dim3(32, 24), dim3(256), 0, stream, Wc, Wi, 768, Wp, 2048);
    hipLaunchKernelGGL(pack_t, dim3(12, 12), dim3(256), 0, stream, Wq, Wq, 768, Wqt, 768);
    hipLaunchKernelGGL(cvt_bf16, dim3(2048), dim3(256), 0, stream,
                       img_feat, Abf, (long)(51200ull * 2048u / 8u));
    hipLaunchKernelGGL(cvt_bf16, dim3(1024), dim3(256), 0, stream,
                       ques_feat, Qbf, (long)(7168u * 768u / 8u));

    // imgCE(bf16) = img_feat @ [Wc|Wi] + [bc|bi]   (M=51200, N=1536, K=2048)
    hipLaunchKernelGGL(HIP_KERNEL_NAME(gemm8<1>), dim3(1200), dim3(512), 0, stream,
                       Abf, Wp, bc, bi, 768, (void*)imgCE, 1536, 2048, 6);
    // qe(bf16) = ques_feat @ Wq + bq               (M=7168, N=768, K=768)
    hipLaunchKernelGGL(HIP_KERNEL_NAME(gemm8<1>), dim3(84), dim3(512), 0, stream,
                       Qbf, Wqt, bq, bq, 768, (void*)qe, 768, 768, 3);

    hipLaunchKernelGGL(fused_kernel, dim3(512), dim3(256), 0, stream,
                       ques_feat, Qbf, qe, imgCE, Abf,
                       g1, b1, g2, b2, g3, b3, g4, b4, g5, b5,
                       wqa, bqa, wia, bia, out_img, out_q);
}